// Round 7
// baseline (580.725 us; speedup 1.0000x reference)
//
#include <hip/hip_runtime.h>
#include <math.h>

#define N_NODES 50000
#define N_EDGES 800000
#define D_IN    128
#define H_DIM   256
#define L_LAYERS 3
#define SCAN_BLOCKS ((N_NODES + 255) / 256)   // 196
#define FUSED_BLOCKS ((N_NODES + 63) / 64)    // 782 (tail block: 16 valid rows)

typedef _Float16 f16x8 __attribute__((ext_vector_type(8)));
typedef _Float16 f16x4 __attribute__((ext_vector_type(4)));
typedef float    f32x4 __attribute__((ext_vector_type(4)));

// ---------------- CSR build ----------------
// counts zeroed via hipMemsetAsync. hist's atomicAdd returns the edge's rank
// within its dst bucket -> fill is atomic-free.

__global__ __launch_bounds__(256) void hist_kernel(const int* __restrict__ dst,
                                                   int* __restrict__ counts,
                                                   int* __restrict__ rank, int e_cnt) {
    int e = blockIdx.x * 256 + threadIdx.x;
    if (e < e_cnt) rank[e] = atomicAdd(&counts[dst[e]], 1);
}

__global__ __launch_bounds__(256) void scanA_kernel(const int* __restrict__ counts,
                                                    int* __restrict__ blocksum,
                                                    float* __restrict__ dinv, int n) {
    __shared__ int s[256];
    int t = threadIdx.x;
    int i = blockIdx.x * 256 + t;
    int v = (i < n) ? counts[i] : 0;
    if (i < n) dinv[i] = rsqrtf((float)(v + 1));
    s[t] = v;
    __syncthreads();
#pragma unroll
    for (int d = 128; d > 0; d >>= 1) {
        if (t < d) s[t] += s[t + d];
        __syncthreads();
    }
    if (t == 0) blocksum[blockIdx.x] = s[0];
}

__global__ __launch_bounds__(256) void scanB_kernel(int* __restrict__ blocksum,
                                                    int* __restrict__ offsets,
                                                    int nblocks, int n, int total) {
    __shared__ int s[256];
    int t = threadIdx.x;
    int v = (t < nblocks) ? blocksum[t] : 0;
    s[t] = v;
    __syncthreads();
#pragma unroll
    for (int d = 1; d < 256; d <<= 1) {
        int x = (t >= d) ? s[t - d] : 0;
        __syncthreads();
        s[t] += x;
        __syncthreads();
    }
    if (t < nblocks) blocksum[t] = s[t] - v;
    if (t == 0) offsets[n] = total;
}

__global__ __launch_bounds__(256) void scanC_kernel(const int* __restrict__ counts,
                                                    const int* __restrict__ blocksum,
                                                    int* __restrict__ offsets, int n) {
    __shared__ int s[256];
    int t = threadIdx.x;
    int i = blockIdx.x * 256 + t;
    int v = (i < n) ? counts[i] : 0;
    s[t] = v;
    __syncthreads();
#pragma unroll
    for (int d = 1; d < 256; d <<= 1) {
        int x = (t >= d) ? s[t - d] : 0;
        __syncthreads();
        s[t] += x;
        __syncthreads();
    }
    if (i < n) offsets[i] = blocksum[blockIdx.x] + s[t] - v;
}

__global__ __launch_bounds__(256) void fill_kernel(const int* __restrict__ src,
                                                   const int* __restrict__ dst,
                                                   const int* __restrict__ offsets,
                                                   const int* __restrict__ rank,
                                                   const float* __restrict__ dinv,
                                                   int2* __restrict__ csr, int e_cnt) {
    int e = blockIdx.x * 256 + threadIdx.x;
    if (e < e_cnt) {
        int d = dst[e];
        int pos = offsets[d] + rank[e];
        int s = src[e];
        csr[pos] = make_int2(s, __float_as_int(dinv[s]));
    }
}

// ---------------- fused GCN layer: aggregate + MFMA transform, 64-node blocks ----------------
// Block = 64 nodes, 4 waves. Phase 1: wave w aggregates nodes nb+16w..nb+16w+15
// (exact round-0 gather loop per node) into LDS A-tile [64][264] (+16B row pad).
// Phase 2: wave w computes col-quarter w: 64x64 output (4 m-tiles x 4 col-tiles,
// 256 MFMAs), W hi/lo read direct from frag-linear global. 64-node blocks cut
// per-dispatch W L2 traffic 800->200 MB vs 16-node blocks (W read is 256KB/block
// regardless of node count -> amortize over 4x rows). Tail block zero-fills.

__global__ __launch_bounds__(256) void fused_layer(const _Float16* __restrict__ h_in,
                                                   const int* __restrict__ offsets,
                                                   const int2* __restrict__ csr,
                                                   const float* __restrict__ dinv,
                                                   const _Float16* __restrict__ WhL,
                                                   const _Float16* __restrict__ WlL,
                                                   const float* __restrict__ bias,
                                                   _Float16* __restrict__ h_out, int n) {
    __shared__ _Float16 Alds[64][264];        // 264 = 256 + 8 f16 pad (16B)
    int wave = threadIdx.x >> 6;
    int lane = threadIdx.x & 63;
    int nb = blockIdx.x * 64;
    int c = lane * 4;

    // ---- phase 1: aggregate 16 nodes per wave ----
    for (int i = 0; i < 16; ++i) {
        int row = wave * 16 + i;
        int v = nb + row;
        if (v >= n) {
            f16x4 z = (f16x4)((_Float16)0.0f);
            *(f16x4*)&Alds[row][c] = z;
            continue;
        }
        float dv = dinv[v];
        f16x4 self = *(const f16x4*)(h_in + (size_t)v * H_DIM + c);
        float ax = dv * (float)self[0];
        float ay = dv * (float)self[1];
        float az = dv * (float)self[2];
        float aw = dv * (float)self[3];

        int e  = offsets[v];
        int e1 = offsets[v + 1];

        for (; e + 15 < e1; e += 16) {
            int2 rec[16]; f16x4 r_[16];
#pragma unroll
            for (int j = 0; j < 16; ++j) rec[j] = csr[e + j];
#pragma unroll
            for (int j = 0; j < 16; ++j) r_[j] = *(const f16x4*)(h_in + (size_t)rec[j].x * H_DIM + c);
#pragma unroll
            for (int j = 0; j < 16; ++j) {
                float w = __int_as_float(rec[j].y);
                ax += w * (float)r_[j][0];
                ay += w * (float)r_[j][1];
                az += w * (float)r_[j][2];
                aw += w * (float)r_[j][3];
            }
        }
        if (e + 7 < e1) {
            int2 rec[8]; f16x4 r_[8];
#pragma unroll
            for (int j = 0; j < 8; ++j) rec[j] = csr[e + j];
#pragma unroll
            for (int j = 0; j < 8; ++j) r_[j] = *(const f16x4*)(h_in + (size_t)rec[j].x * H_DIM + c);
#pragma unroll
            for (int j = 0; j < 8; ++j) {
                float w = __int_as_float(rec[j].y);
                ax += w * (float)r_[j][0];
                ay += w * (float)r_[j][1];
                az += w * (float)r_[j][2];
                aw += w * (float)r_[j][3];
            }
            e += 8;
        }
        if (e + 3 < e1) {
            int2 rec[4]; f16x4 r_[4];
#pragma unroll
            for (int j = 0; j < 4; ++j) rec[j] = csr[e + j];
#pragma unroll
            for (int j = 0; j < 4; ++j) r_[j] = *(const f16x4*)(h_in + (size_t)rec[j].x * H_DIM + c);
#pragma unroll
            for (int j = 0; j < 4; ++j) {
                float w = __int_as_float(rec[j].y);
                ax += w * (float)r_[j][0];
                ay += w * (float)r_[j][1];
                az += w * (float)r_[j][2];
                aw += w * (float)r_[j][3];
            }
            e += 4;
        }
        if (e + 1 < e1) {
            int2 r0 = csr[e], r1 = csr[e + 1];
            f16x4 a = *(const f16x4*)(h_in + (size_t)r0.x * H_DIM + c);
            f16x4 b = *(const f16x4*)(h_in + (size_t)r1.x * H_DIM + c);
            float w0 = __int_as_float(r0.y), w1 = __int_as_float(r1.y);
            ax += w0 * (float)a[0] + w1 * (float)b[0];
            ay += w0 * (float)a[1] + w1 * (float)b[1];
            az += w0 * (float)a[2] + w1 * (float)b[2];
            aw += w0 * (float)a[3] + w1 * (float)b[3];
            e += 2;
        }
        if (e < e1) {
            int2 r0 = csr[e];
            f16x4 a = *(const f16x4*)(h_in + (size_t)r0.x * H_DIM + c);
            float w0 = __int_as_float(r0.y);
            ax += w0 * (float)a[0]; ay += w0 * (float)a[1];
            az += w0 * (float)a[2]; aw += w0 * (float)a[3];
        }
        f16x4 o;
        o[0] = (_Float16)(ax * dv);
        o[1] = (_Float16)(ay * dv);
        o[2] = (_Float16)(az * dv);
        o[3] = (_Float16)(aw * dv);
        *(f16x4*)&Alds[row][c] = o;
    }
    __syncthreads();

    // ---- phase 2: 64x64 MFMA transform, col-quarter = wave, 4 m-tiles ----
    int mrow = lane & 15;
    int g    = lane >> 4;
    const _Float16* Wh = WhL + (size_t)wave * 2048 + (size_t)lane * 8;
    const _Float16* Wl = WlL + (size_t)wave * 2048 + (size_t)lane * 8;

    f32x4 acc2[4][4];                         // [mt][cc]
#pragma unroll
    for (int mt = 0; mt < 4; ++mt)
#pragma unroll
        for (int cc = 0; cc < 4; ++cc) acc2[mt][cc] = (f32x4)(0.0f);

#pragma unroll
    for (int kc = 0; kc < 8; ++kc) {
        f16x8 a[4];
#pragma unroll
        for (int mt = 0; mt < 4; ++mt)
            a[mt] = *(const f16x8*)&Alds[mt * 16 + mrow][kc * 32 + g * 8];
#pragma unroll
        for (int cc = 0; cc < 4; ++cc) {
            f16x8 bh = *(const f16x8*)(Wh + kc * 8192 + cc * 512);
            f16x8 bl = *(const f16x8*)(Wl + kc * 8192 + cc * 512);
#pragma unroll
            for (int mt = 0; mt < 4; ++mt) {
                acc2[mt][cc] = __builtin_amdgcn_mfma_f32_16x16x32_f16(a[mt], bh, acc2[mt][cc], 0, 0, 0);
                acc2[mt][cc] = __builtin_amdgcn_mfma_f32_16x16x32_f16(a[mt], bl, acc2[mt][cc], 0, 0, 0);
            }
        }
    }

    int colq = lane & 15;
    int rowq = g * 4;
#pragma unroll
    for (int cc = 0; cc < 4; ++cc) {
        int col = wave * 64 + cc * 16 + colq;
        float b = bias[col];
#pragma unroll
        for (int mt = 0; mt < 4; ++mt) {
#pragma unroll
            for (int r = 0; r < 4; ++r) {
                int row = nb + mt * 16 + rowq + r;
                if (row < n) {
                    float vv = acc2[mt][cc][r] + b;
                    vv = fmaxf(vv, 0.f);
                    h_out[(size_t)row * H_DIM + col] = (_Float16)vv;
                }
            }
        }
    }
}

// ---------------- weight pre-convert: fp32 [K,256] -> frag-linear f16 hi/lo ----------------
// dst = base + (k>>5)*8192 + (n>>4)*512 + ((k&31)>>3)*128 + (n&15)*8 + (k&7)

#define WCONV_TOTAL 294912

__global__ __launch_bounds__(256) void wconv_kernel(const float* __restrict__ W_enc,
                                                    const float* __restrict__ W_g,
                                                    const float* __restrict__ W_out,
                                                    _Float16* __restrict__ whi,
                                                    _Float16* __restrict__ wlo) {
    int gid = blockIdx.x * 256 + threadIdx.x;
    if (gid >= WCONV_TOTAL) return;
    const float* src; int base, e;
    if (gid < 32768)       { src = W_enc; base = 0;      e = gid; }
    else if (gid < 229376) { src = W_g;   base = 32768;  e = gid - 32768; }
    else                   { src = W_out; base = 229376; e = gid - 229376; }
    int k = e >> 8;
    int n = e & 255;
    float x = src[e];
    _Float16 hb = (_Float16)x;
    _Float16 lb = (_Float16)(x - (float)hb);
    int dst = base + (k >> 5) * 8192 + (n >> 4) * 512 + ((k & 31) >> 3) * 128
            + (n & 15) * 8 + (k & 7);
    whi[dst] = hb;
    wlo[dst] = lb;
}

// ---------------- col-quarter MFMA GEMM (encoder + head) ----------------
// ROUND-1 KNOWN-GOOD CONFIG (depth-2 A prefetch, launch_bounds(256,4)).

template <int KC, int AMODE, int OUT16>
__global__ __launch_bounds__(256, 4) void mfma_gemm(const float* __restrict__ Af,
                                                    const _Float16* __restrict__ A16,
                                                    const _Float16* __restrict__ WhG,
                                                    const _Float16* __restrict__ WlG,
                                                    const float* __restrict__ bias,
                                                    float* __restrict__ Cf,
                                                    _Float16* __restrict__ Ch,
                                                    int n, int relu) {
    constexpr int K   = KC * 32;
    constexpr int PKC = (KC >= 8) ? 4 : KC;   // kc per staging phase
    constexpr int NPH = KC / PKC;
    __shared__ _Float16 Wlds[PKC * 2 * 2048]; // [pk][hi/lo][c(4)][lane(64)][j(8)] = 32 KB

    int t = threadIdx.x;
    int w = t >> 6;
    int lane = t & 63;
    int q  = blockIdx.x >> 8;
    int rt = blockIdx.x & 255;
    if (rt * 256 >= n) return;
    int colbase = q * 64;
    int mrow = lane & 15;
    int koct = (lane >> 4) * 8;
    int rbase = rt * 256 + w * 64;

    int rows[4];
#pragma unroll
    for (int mt = 0; mt < 4; ++mt) {
        int r = rbase + mt * 16 + mrow;
        rows[mt] = (r < n) ? r : (n - 1);     // clamp: dup rows, never stored
    }

    f32x4 acc[4][4];
#pragma unroll
    for (int mt = 0; mt < 4; ++mt)
#pragma unroll
        for (int c = 0; c < 4; ++c)
            acc[mt][c] = (f32x4)(0.0f);

    // ---- A register pipeline ----
    f16x8 a16p[2][4];                 // AMODE 1: depth-2
    float4 af0[4], af1[4];            // AMODE 0: depth-1
    if (AMODE == 1) {
#pragma unroll
        for (int mt = 0; mt < 4; ++mt) {
            a16p[0][mt] = *(const f16x8*)(A16 + (size_t)rows[mt] * K + koct);
            a16p[1][mt] = *(const f16x8*)(A16 + (size_t)rows[mt] * K + 32 + koct);
        }
    } else {
#pragma unroll
        for (int mt = 0; mt < 4; ++mt) {
            const float* p = Af + (size_t)rows[mt] * K + koct;
            af0[mt] = *(const float4*)p;
            af1[mt] = *(const float4*)(p + 4);
        }
    }

#pragma unroll
    for (int ph = 0; ph < NPH; ++ph) {
        if (ph) __syncthreads();              // all waves done reading previous phase
#pragma unroll
        for (int pk = 0; pk < PKC; ++pk) {
            int kc = ph * PKC + pk;
            __builtin_amdgcn_global_load_lds(
                (const __attribute__((address_space(1))) unsigned int*)(WhG + (size_t)kc * 8192 + q * 2048 + t * 8),
                (__attribute__((address_space(3))) unsigned int*)(&Wlds[(pk * 2 + 0) * 2048 + t * 8]), 16, 0, 0);
            __builtin_amdgcn_global_load_lds(
                (const __attribute__((address_space(1))) unsigned int*)(WlG + (size_t)kc * 8192 + q * 2048 + t * 8),
                (__attribute__((address_space(3))) unsigned int*)(&Wlds[(pk * 2 + 1) * 2048 + t * 8]), 16, 0, 0);
        }
        __syncthreads();

#pragma unroll
        for (int pk = 0; pk < PKC; ++pk) {
            int kc = ph * PKC + pk;
            f16x8 ah[4], al[4];
            if (AMODE == 0) {
#pragma unroll
                for (int mt = 0; mt < 4; ++mt) {
                    float4 c0 = af0[mt], c1 = af1[mt];
                    if (kc + 1 < KC) {
                        const float* p = Af + (size_t)rows[mt] * K + (kc + 1) * 32 + koct;
                        af0[mt] = *(const float4*)p;
                        af1[mt] = *(const float4*)(p + 4);
                    }
                    float xs[8] = {c0.x, c0.y, c0.z, c0.w, c1.x, c1.y, c1.z, c1.w};
                    f16x8 H, L;
#pragma unroll
                    for (int j = 0; j < 8; ++j) {
                        _Float16 hb = (_Float16)xs[j];
                        H[j] = hb;
                        L[j] = (_Float16)(xs[j] - (float)hb);
                    }
                    ah[mt] = H;
                    al[mt] = L;
                }
            }

#pragma unroll
            for (int c = 0; c < 4; ++c) {
                f16x8 bh = *(const f16x8*)&Wlds[(pk * 2 + 0) * 2048 + c * 512 + lane * 8];
                f16x8 bl = *(const f16x8*)&Wlds[(pk * 2 + 1) * 2048 + c * 512 + lane * 8];
#pragma unroll
                for (int mt = 0; mt < 4; ++mt) {
                    if (AMODE == 1) {
                        f16x8 a = a16p[kc & 1][mt];
                        acc[mt][c] = __builtin_amdgcn_mfma_f32_16x16x32_f16(a, bh, acc[mt][c], 0, 0, 0);
                        acc[mt][c] = __builtin_amdgcn_mfma_f32_16x16x32_f16(a, bl, acc[mt][c], 0, 0, 0);
                    } else {
                        acc[mt][c] = __builtin_amdgcn_mfma_f32_16x16x32_f16(ah[mt], bh, acc[mt][c], 0, 0, 0);
                        acc[mt][c] = __builtin_amdgcn_mfma_f32_16x16x32_f16(ah[mt], bl, acc[mt][c], 0, 0, 0);
                        acc[mt][c] = __builtin_amdgcn_mfma_f32_16x16x32_f16(al[mt], bh, acc[mt][c], 0, 0, 0);
                    }
                }
            }

            if (AMODE == 1 && kc + 2 < KC) {
#pragma unroll
                for (int mt = 0; mt < 4; ++mt)
                    a16p[kc & 1][mt] = *(const f16x8*)(A16 + (size_t)rows[mt] * K + (kc + 2) * 32 + koct);
            }
        }
    }

    // ---- epilogue: C/D layout col=lane&15, row=(lane>>4)*4+reg ----
    int colq = lane & 15;
    int rowq = (lane >> 4) * 4;
#pragma unroll
    for (int c = 0; c < 4; ++c) {
        int col = colbase + c * 16 + colq;
        float b = bias[col];
#pragma unroll
        for (int mt = 0; mt < 4; ++mt) {
            int rb = rbase + mt * 16 + rowq;
#pragma unroll
            for (int r = 0; r < 4; ++r) {
                int row = rb + r;
                if (row < n) {
                    float v = acc[mt][c][r] + b;
                    if (relu) v = fmaxf(v, 0.f);
                    if (OUT16) Ch[(size_t)row * H_DIM + col] = (_Float16)v;
                    else       Cf[(size_t)row * H_DIM + col] = v;
                }
            }
        }
    }
}

// ---------------- launch ----------------

extern "C" void kernel_launch(void* const* d_in, const int* in_sizes, int n_in,
                              void* d_out, int out_size, void* d_ws, size_t ws_size,
                              hipStream_t stream) {
    const float* x     = (const float*)d_in[0];
    const int*   ei    = (const int*)d_in[1];
    const float* W_enc = (const float*)d_in[3];
    const float* b_enc = (const float*)d_in[4];
    const float* W_g   = (const float*)d_in[5];
    const float* b_g   = (const float*)d_in[6];
    const float* W_out = (const float*)d_in[7];
    const float* b_out = (const float*)d_in[8];
    float* out = (float*)d_out;

    char* ws = (char*)d_ws;
    size_t off = 0;
    auto alloc = [&](size_t bytes) -> void* {
        void* p = ws + off;
        off = (off + bytes + 255) & ~(size_t)255;
        return p;
    };
    int*       counts   = (int*)alloc((size_t)N_NODES * 4);
    int*       offsets  = (int*)alloc((size_t)(N_NODES + 1) * 4);
    float*     dinv     = (float*)alloc((size_t)N_NODES * 4);
    int*       blocksum = (int*)alloc((size_t)SCAN_BLOCKS * 4);
    int*       rank     = (int*)alloc((size_t)N_EDGES * 4);
    int2*      csr      = (int2*)alloc((size_t)N_EDGES * 8);
    _Float16*  h16      = (_Float16*)alloc((size_t)N_NODES * H_DIM * 2);
    _Float16*  hbuf     = (_Float16*)alloc((size_t)N_NODES * H_DIM * 2);
    _Float16*  whi      = (_Float16*)alloc((size_t)WCONV_TOTAL * 2);
    _Float16*  wlo      = (_Float16*)alloc((size_t)WCONV_TOTAL * 2);

    const int* src = ei;
    const int* dst = ei + N_EDGES;

    hipMemsetAsync(counts, 0, (size_t)N_NODES * 4, stream);
    hist_kernel<<<(N_EDGES + 255) / 256, 256, 0, stream>>>(dst, counts, rank, N_EDGES);
    scanA_kernel<<<SCAN_BLOCKS, 256, 0, stream>>>(counts, blocksum, dinv, N_NODES);
    scanB_kernel<<<1, 256, 0, stream>>>(blocksum, offsets, SCAN_BLOCKS, N_NODES, N_EDGES);
    scanC_kernel<<<SCAN_BLOCKS, 256, 0, stream>>>(counts, blocksum, offsets, N_NODES);
    fill_kernel<<<(N_EDGES + 255) / 256, 256, 0, stream>>>(src, dst, offsets, rank, dinv,
                                                           csr, N_EDGES);
    wconv_kernel<<<(WCONV_TOTAL + 255) / 256, 256, 0, stream>>>(W_enc, W_g, W_out, whi, wlo);

    // encoder: h1 = relu(x @ W_enc + b_enc)  — KC=4 (K=128), fp32 A inline-split
    mfma_gemm<4, 0, 1><<<1024, 256, 0, stream>>>(x, (const _Float16*)nullptr,
                                                 whi, wlo, b_enc,
                                                 (float*)nullptr, h16, N_NODES, 1);
    // 3 fused GCN layers (aggregate + transform, 64-node blocks, ping-pong h)
    _Float16* ping = h16;
    _Float16* pong = hbuf;
    for (int l = 0; l < L_LAYERS; ++l) {
        fused_layer<<<FUSED_BLOCKS, 256, 0, stream>>>(ping, offsets, csr, dinv,
                                                      whi + 32768 + (size_t)l * 65536,
                                                      wlo + 32768 + (size_t)l * 65536,
                                                      b_g + (size_t)l * H_DIM,
                                                      pong, N_NODES);
        _Float16* tmp = ping; ping = pong; pong = tmp;
    }
    // output head (no relu), f16 A, fp32 out
    mfma_gemm<8, 1, 0><<<1024, 256, 0, stream>>>((const float*)nullptr, ping,
                                                 whi + 229376, wlo + 229376, b_out,
                                                 out, (_Float16*)nullptr, N_NODES, 0);
}

// Round 8
// 510.187 us; speedup vs baseline: 1.1383x; 1.1383x over previous
//
#include <hip/hip_runtime.h>
#include <math.h>

#define N_NODES 50000
#define N_EDGES 800000
#define D_IN    128
#define H_DIM   256
#define L_LAYERS 3
#define SCAN_BLOCKS ((N_NODES + 255) / 256)   // 196

typedef _Float16 f16x8 __attribute__((ext_vector_type(8)));
typedef _Float16 f16x4 __attribute__((ext_vector_type(4)));
typedef float    f32x4 __attribute__((ext_vector_type(4)));
typedef unsigned long long u64;

// ---------------- CSR build ----------------
// counts zeroed via hipMemsetAsync. hist's atomicAdd returns the edge's rank
// within its dst bucket -> fill is atomic-free. rank stored non-temporal
// (write-once stream, skip RFO/alloc).

__global__ __launch_bounds__(256) void hist_kernel(const int* __restrict__ dst,
                                                   int* __restrict__ counts,
                                                   int* __restrict__ rank, int e_cnt) {
    int e = blockIdx.x * 256 + threadIdx.x;
    if (e < e_cnt) {
        int r = atomicAdd(&counts[dst[e]], 1);
        __builtin_nontemporal_store(r, &rank[e]);
    }
}

__global__ __launch_bounds__(256) void scanA_kernel(const int* __restrict__ counts,
                                                    int* __restrict__ blocksum,
                                                    float* __restrict__ dinv, int n) {
    __shared__ int s[256];
    int t = threadIdx.x;
    int i = blockIdx.x * 256 + t;
    int v = (i < n) ? counts[i] : 0;
    if (i < n) dinv[i] = rsqrtf((float)(v + 1));
    s[t] = v;
    __syncthreads();
#pragma unroll
    for (int d = 128; d > 0; d >>= 1) {
        if (t < d) s[t] += s[t + d];
        __syncthreads();
    }
    if (t == 0) blocksum[blockIdx.x] = s[0];
}

__global__ __launch_bounds__(256) void scanB_kernel(int* __restrict__ blocksum,
                                                    int* __restrict__ offsets,
                                                    int nblocks, int n, int total) {
    __shared__ int s[256];
    int t = threadIdx.x;
    int v = (t < nblocks) ? blocksum[t] : 0;
    s[t] = v;
    __syncthreads();
#pragma unroll
    for (int d = 1; d < 256; d <<= 1) {
        int x = (t >= d) ? s[t - d] : 0;
        __syncthreads();
        s[t] += x;
        __syncthreads();
    }
    if (t < nblocks) blocksum[t] = s[t] - v;
    if (t == 0) offsets[n] = total;
}

__global__ __launch_bounds__(256) void scanC_kernel(const int* __restrict__ counts,
                                                    const int* __restrict__ blocksum,
                                                    int* __restrict__ offsets, int n) {
    __shared__ int s[256];
    int t = threadIdx.x;
    int i = blockIdx.x * 256 + t;
    int v = (i < n) ? counts[i] : 0;
    s[t] = v;
    __syncthreads();
#pragma unroll
    for (int d = 1; d < 256; d <<= 1) {
        int x = (t >= d) ? s[t - d] : 0;
        __syncthreads();
        s[t] += x;
        __syncthreads();
    }
    if (i < n) offsets[i] = blocksum[blockIdx.x] + s[t] - v;
}

// fill: atomic-free, ONE scattered 8B record per edge (src, dinv[src]),
// stored NON-TEMPORAL: skips the RFO read of the target line (random scatter
// -> L2 can't merge bucket-mates before eviction; round-0 measured 6.5x
// write amplification on the cached path).

__global__ __launch_bounds__(256) void fill_kernel(const int* __restrict__ src,
                                                   const int* __restrict__ dst,
                                                   const int* __restrict__ offsets,
                                                   const int* __restrict__ rank,
                                                   const float* __restrict__ dinv,
                                                   int2* __restrict__ csr, int e_cnt) {
    int e = blockIdx.x * 256 + threadIdx.x;
    if (e < e_cnt) {
        int d = dst[e];
        int pos = offsets[d] + rank[e];
        int s = src[e];
        unsigned int wb = (unsigned int)__float_as_int(dinv[s]);
        u64 rec = ((u64)wb << 32) | (unsigned int)s;   // low word = x = src
        __builtin_nontemporal_store(rec, (u64*)&csr[pos]);
    }
}

// ---------------- aggregation: round-0 structure (best measured) + int2 csr ----------------
// Wave = one node. lane covers cols lane*4..lane*4+3 (f16x4, 8B/lane, full 512B
// row per edge, every fetched byte used). Unroll 16/8/4/2/1. FETCH ~188MB is the
// per-XCD compulsory floor for this random gather (XCD-pin, persistence, and two
// fusion variants all measured worse) — gather loop frozen. Output stored
// non-temporal: consumed only by the NEXT kernel; keep h lines L2-resident.

__global__ __launch_bounds__(256) void aggregate_kernel(const _Float16* __restrict__ h,
                                                        const int* __restrict__ offsets,
                                                        const int2* __restrict__ csr,
                                                        const float* __restrict__ dinv,
                                                        _Float16* __restrict__ outp, int n) {
    int wave = threadIdx.x >> 6;
    int lane = threadIdx.x & 63;
    int v = blockIdx.x * 4 + wave;
    if (v >= n) return;
    int c = lane * 4;
    float dv = dinv[v];
    f16x4 self = *(const f16x4*)(h + (size_t)v * H_DIM + c);
    float ax = dv * (float)self[0];
    float ay = dv * (float)self[1];
    float az = dv * (float)self[2];
    float aw = dv * (float)self[3];

    int e  = offsets[v];
    int e1 = offsets[v + 1];

    for (; e + 15 < e1; e += 16) {
        int2 rec[16]; f16x4 r_[16];
#pragma unroll
        for (int j = 0; j < 16; ++j) rec[j] = csr[e + j];
#pragma unroll
        for (int j = 0; j < 16; ++j) r_[j] = *(const f16x4*)(h + (size_t)rec[j].x * H_DIM + c);
#pragma unroll
        for (int j = 0; j < 16; ++j) {
            float w = __int_as_float(rec[j].y);
            ax += w * (float)r_[j][0];
            ay += w * (float)r_[j][1];
            az += w * (float)r_[j][2];
            aw += w * (float)r_[j][3];
        }
    }
    if (e + 7 < e1) {
        int2 rec[8]; f16x4 r_[8];
#pragma unroll
        for (int j = 0; j < 8; ++j) rec[j] = csr[e + j];
#pragma unroll
        for (int j = 0; j < 8; ++j) r_[j] = *(const f16x4*)(h + (size_t)rec[j].x * H_DIM + c);
#pragma unroll
        for (int j = 0; j < 8; ++j) {
            float w = __int_as_float(rec[j].y);
            ax += w * (float)r_[j][0];
            ay += w * (float)r_[j][1];
            az += w * (float)r_[j][2];
            aw += w * (float)r_[j][3];
        }
        e += 8;
    }
    if (e + 3 < e1) {
        int2 rec[4]; f16x4 r_[4];
#pragma unroll
        for (int j = 0; j < 4; ++j) rec[j] = csr[e + j];
#pragma unroll
        for (int j = 0; j < 4; ++j) r_[j] = *(const f16x4*)(h + (size_t)rec[j].x * H_DIM + c);
#pragma unroll
        for (int j = 0; j < 4; ++j) {
            float w = __int_as_float(rec[j].y);
            ax += w * (float)r_[j][0];
            ay += w * (float)r_[j][1];
            az += w * (float)r_[j][2];
            aw += w * (float)r_[j][3];
        }
        e += 4;
    }
    if (e + 1 < e1) {
        int2 r0 = csr[e], r1 = csr[e + 1];
        f16x4 a = *(const f16x4*)(h + (size_t)r0.x * H_DIM + c);
        f16x4 b = *(const f16x4*)(h + (size_t)r1.x * H_DIM + c);
        float w0 = __int_as_float(r0.y), w1 = __int_as_float(r1.y);
        ax += w0 * (float)a[0] + w1 * (float)b[0];
        ay += w0 * (float)a[1] + w1 * (float)b[1];
        az += w0 * (float)a[2] + w1 * (float)b[2];
        aw += w0 * (float)a[3] + w1 * (float)b[3];
        e += 2;
    }
    if (e < e1) {
        int2 r0 = csr[e];
        f16x4 a = *(const f16x4*)(h + (size_t)r0.x * H_DIM + c);
        float w0 = __int_as_float(r0.y);
        ax += w0 * (float)a[0]; ay += w0 * (float)a[1];
        az += w0 * (float)a[2]; aw += w0 * (float)a[3];
    }
    f16x4 o;
    o[0] = (_Float16)(ax * dv);
    o[1] = (_Float16)(ay * dv);
    o[2] = (_Float16)(az * dv);
    o[3] = (_Float16)(aw * dv);
    u64 bits;
    __builtin_memcpy(&bits, &o, 8);
    __builtin_nontemporal_store(bits, (u64*)(outp + (size_t)v * H_DIM + c));
}

// ---------------- weight pre-convert: fp32 [K,256] -> frag-linear f16 hi/lo ----------------
// dst = base + (k>>5)*8192 + (n>>4)*512 + ((k&31)>>3)*128 + (n&15)*8 + (k&7)

#define WCONV_TOTAL 294912

__global__ __launch_bounds__(256) void wconv_kernel(const float* __restrict__ W_enc,
                                                    const float* __restrict__ W_g,
                                                    const float* __restrict__ W_out,
                                                    _Float16* __restrict__ whi,
                                                    _Float16* __restrict__ wlo) {
    int gid = blockIdx.x * 256 + threadIdx.x;
    if (gid >= WCONV_TOTAL) return;
    const float* src; int base, e;
    if (gid < 32768)       { src = W_enc; base = 0;      e = gid; }
    else if (gid < 229376) { src = W_g;   base = 32768;  e = gid - 32768; }
    else                   { src = W_out; base = 229376; e = gid - 229376; }
    int k = e >> 8;
    int n = e & 255;
    float x = src[e];
    _Float16 hb = (_Float16)x;
    _Float16 lb = (_Float16)(x - (float)hb);
    int dst = base + (k >> 5) * 8192 + (n >> 4) * 512 + ((k & 31) >> 3) * 128
            + (n & 15) * 8 + (k & 7);
    whi[dst] = hb;
    wlo[dst] = lb;
}

// ---------------- col-quarter MFMA GEMM (encoder + head) ----------------
// ROUND-1 KNOWN-GOOD CONFIG (depth-2 A prefetch, launch_bounds(256,4)).
// fp32 output (head) stored non-temporal: never re-read, saves 51MB RFO.

template <int KC, int AMODE, int OUT16>
__global__ __launch_bounds__(256, 4) void mfma_gemm(const float* __restrict__ Af,
                                                    const _Float16* __restrict__ A16,
                                                    const _Float16* __restrict__ WhG,
                                                    const _Float16* __restrict__ WlG,
                                                    const float* __restrict__ bias,
                                                    float* __restrict__ Cf,
                                                    _Float16* __restrict__ Ch,
                                                    int n, int relu) {
    constexpr int K   = KC * 32;
    constexpr int PKC = (KC >= 8) ? 4 : KC;   // kc per staging phase
    constexpr int NPH = KC / PKC;
    __shared__ _Float16 Wlds[PKC * 2 * 2048]; // [pk][hi/lo][c(4)][lane(64)][j(8)] = 32 KB

    int t = threadIdx.x;
    int w = t >> 6;
    int lane = t & 63;
    int q  = blockIdx.x >> 8;
    int rt = blockIdx.x & 255;
    if (rt * 256 >= n) return;
    int colbase = q * 64;
    int mrow = lane & 15;
    int koct = (lane >> 4) * 8;
    int rbase = rt * 256 + w * 64;

    int rows[4];
#pragma unroll
    for (int mt = 0; mt < 4; ++mt) {
        int r = rbase + mt * 16 + mrow;
        rows[mt] = (r < n) ? r : (n - 1);     // clamp: dup rows, never stored
    }

    f32x4 acc[4][4];
#pragma unroll
    for (int mt = 0; mt < 4; ++mt)
#pragma unroll
        for (int c = 0; c < 4; ++c)
            acc[mt][c] = (f32x4)(0.0f);

    // ---- A register pipeline ----
    f16x8 a16p[2][4];                 // AMODE 1: depth-2
    float4 af0[4], af1[4];            // AMODE 0: depth-1
    if (AMODE == 1) {
#pragma unroll
        for (int mt = 0; mt < 4; ++mt) {
            a16p[0][mt] = *(const f16x8*)(A16 + (size_t)rows[mt] * K + koct);
            a16p[1][mt] = *(const f16x8*)(A16 + (size_t)rows[mt] * K + 32 + koct);
        }
    } else {
#pragma unroll
        for (int mt = 0; mt < 4; ++mt) {
            const float* p = Af + (size_t)rows[mt] * K + koct;
            af0[mt] = *(const float4*)p;
            af1[mt] = *(const float4*)(p + 4);
        }
    }

#pragma unroll
    for (int ph = 0; ph < NPH; ++ph) {
        if (ph) __syncthreads();              // all waves done reading previous phase
#pragma unroll
        for (int pk = 0; pk < PKC; ++pk) {
            int kc = ph * PKC + pk;
            __builtin_amdgcn_global_load_lds(
                (const __attribute__((address_space(1))) unsigned int*)(WhG + (size_t)kc * 8192 + q * 2048 + t * 8),
                (__attribute__((address_space(3))) unsigned int*)(&Wlds[(pk * 2 + 0) * 2048 + t * 8]), 16, 0, 0);
            __builtin_amdgcn_global_load_lds(
                (const __attribute__((address_space(1))) unsigned int*)(WlG + (size_t)kc * 8192 + q * 2048 + t * 8),
                (__attribute__((address_space(3))) unsigned int*)(&Wlds[(pk * 2 + 1) * 2048 + t * 8]), 16, 0, 0);
        }
        __syncthreads();

#pragma unroll
        for (int pk = 0; pk < PKC; ++pk) {
            int kc = ph * PKC + pk;
            f16x8 ah[4], al[4];
            if (AMODE == 0) {
#pragma unroll
                for (int mt = 0; mt < 4; ++mt) {
                    float4 c0 = af0[mt], c1 = af1[mt];
                    if (kc + 1 < KC) {
                        const float* p = Af + (size_t)rows[mt] * K + (kc + 1) * 32 + koct;
                        af0[mt] = *(const float4*)p;
                        af1[mt] = *(const float4*)(p + 4);
                    }
                    float xs[8] = {c0.x, c0.y, c0.z, c0.w, c1.x, c1.y, c1.z, c1.w};
                    f16x8 H, L;
#pragma unroll
                    for (int j = 0; j < 8; ++j) {
                        _Float16 hb = (_Float16)xs[j];
                        H[j] = hb;
                        L[j] = (_Float16)(xs[j] - (float)hb);
                    }
                    ah[mt] = H;
                    al[mt] = L;
                }
            }

#pragma unroll
            for (int c = 0; c < 4; ++c) {
                f16x8 bh = *(const f16x8*)&Wlds[(pk * 2 + 0) * 2048 + c * 512 + lane * 8];
                f16x8 bl = *(const f16x8*)&Wlds[(pk * 2 + 1) * 2048 + c * 512 + lane * 8];
#pragma unroll
                for (int mt = 0; mt < 4; ++mt) {
                    if (AMODE == 1) {
                        f16x8 a = a16p[kc & 1][mt];
                        acc[mt][c] = __builtin_amdgcn_mfma_f32_16x16x32_f16(a, bh, acc[mt][c], 0, 0, 0);
                        acc[mt][c] = __builtin_amdgcn_mfma_f32_16x16x32_f16(a, bl, acc[mt][c], 0, 0, 0);
                    } else {
                        acc[mt][c] = __builtin_amdgcn_mfma_f32_16x16x32_f16(ah[mt], bh, acc[mt][c], 0, 0, 0);
                        acc[mt][c] = __builtin_amdgcn_mfma_f32_16x16x32_f16(ah[mt], bl, acc[mt][c], 0, 0, 0);
                        acc[mt][c] = __builtin_amdgcn_mfma_f32_16x16x32_f16(al[mt], bh, acc[mt][c], 0, 0, 0);
                    }
                }
            }

            if (AMODE == 1 && kc + 2 < KC) {
#pragma unroll
                for (int mt = 0; mt < 4; ++mt)
                    a16p[kc & 1][mt] = *(const f16x8*)(A16 + (size_t)rows[mt] * K + (kc + 2) * 32 + koct);
            }
        }
    }

    // ---- epilogue: C/D layout col=lane&15, row=(lane>>4)*4+reg ----
    int colq = lane & 15;
    int rowq = (lane >> 4) * 4;
#pragma unroll
    for (int c = 0; c < 4; ++c) {
        int col = colbase + c * 16 + colq;
        float b = bias[col];
#pragma unroll
        for (int mt = 0; mt < 4; ++mt) {
            int rb = rbase + mt * 16 + rowq;
#pragma unroll
            for (int r = 0; r < 4; ++r) {
                int row = rb + r;
                if (row < n) {
                    float v = acc[mt][c][r] + b;
                    if (relu) v = fmaxf(v, 0.f);
                    if (OUT16) Ch[(size_t)row * H_DIM + col] = (_Float16)v;
                    else       __builtin_nontemporal_store(v, &Cf[(size_t)row * H_DIM + col]);
                }
            }
        }
    }
}

// ---------------- launch ----------------

extern "C" void kernel_launch(void* const* d_in, const int* in_sizes, int n_in,
                              void* d_out, int out_size, void* d_ws, size_t ws_size,
                              hipStream_t stream) {
    const float* x     = (const float*)d_in[0];
    const int*   ei    = (const int*)d_in[1];
    const float* W_enc = (const float*)d_in[3];
    const float* b_enc = (const float*)d_in[4];
    const float* W_g   = (const float*)d_in[5];
    const float* b_g   = (const float*)d_in[6];
    const float* W_out = (const float*)d_in[7];
    const float* b_out = (const float*)d_in[8];
    float* out = (float*)d_out;

    char* ws = (char*)d_ws;
    size_t off = 0;
    auto alloc = [&](size_t bytes) -> void* {
        void* p = ws + off;
        off = (off + bytes + 255) & ~(size_t)255;
        return p;
    };
    int*       counts   = (int*)alloc((size_t)N_NODES * 4);
    int*       offsets  = (int*)alloc((size_t)(N_NODES + 1) * 4);
    float*     dinv     = (float*)alloc((size_t)N_NODES * 4);
    int*       blocksum = (int*)alloc((size_t)SCAN_BLOCKS * 4);
    int*       rank     = (int*)alloc((size_t)N_EDGES * 4);
    int2*      csr      = (int2*)alloc((size_t)N_EDGES * 8);
    _Float16*  h16      = (_Float16*)alloc((size_t)N_NODES * H_DIM * 2);
    _Float16*  agg16    = (_Float16*)alloc((size_t)N_NODES * H_DIM * 2);
    _Float16*  whi      = (_Float16*)alloc((size_t)WCONV_TOTAL * 2);
    _Float16*  wlo      = (_Float16*)alloc((size_t)WCONV_TOTAL * 2);

    const int* src = ei;
    const int* dst = ei + N_EDGES;

    hipMemsetAsync(counts, 0, (size_t)N_NODES * 4, stream);
    hist_kernel<<<(N_EDGES + 255) / 256, 256, 0, stream>>>(dst, counts, rank, N_EDGES);
    scanA_kernel<<<SCAN_BLOCKS, 256, 0, stream>>>(counts, blocksum, dinv, N_NODES);
    scanB_kernel<<<1, 256, 0, stream>>>(blocksum, offsets, SCAN_BLOCKS, N_NODES, N_EDGES);
    scanC_kernel<<<SCAN_BLOCKS, 256, 0, stream>>>(counts, blocksum, offsets, N_NODES);
    fill_kernel<<<(N_EDGES + 255) / 256, 256, 0, stream>>>(src, dst, offsets, rank, dinv,
                                                           csr, N_EDGES);
    wconv_kernel<<<(WCONV_TOTAL + 255) / 256, 256, 0, stream>>>(W_enc, W_g, W_out, whi, wlo);

    // encoder: h1 = relu(x @ W_enc + b_enc)  — KC=4 (K=128), fp32 A inline-split
    mfma_gemm<4, 0, 1><<<1024, 256, 0, stream>>>(x, (const _Float16*)nullptr,
                                                 whi, wlo, b_enc,
                                                 (float*)nullptr, h16, N_NODES, 1);
    // 3 GCN layers
    for (int l = 0; l < L_LAYERS; ++l) {
        aggregate_kernel<<<N_NODES / 4, 256, 0, stream>>>(h16, offsets, csr, dinv,
                                                          agg16, N_NODES);
        mfma_gemm<8, 1, 1><<<1024, 256, 0, stream>>>((const float*)nullptr, agg16,
                                                     whi + 32768 + (size_t)l * 65536,
                                                     wlo + 32768 + (size_t)l * 65536,
                                                     b_g + (size_t)l * H_DIM,
                                                     (float*)nullptr, h16, N_NODES, 1);
    }
    // output head (no relu), f16 A, fp32 out — NT stores
    mfma_gemm<8, 1, 0><<<1024, 256, 0, stream>>>((const float*)nullptr, h16,
                                                 whi + 229376, wlo + 229376, b_out,
                                                 out, (_Float16*)nullptr, N_NODES, 0);
}

// Round 9
// 499.327 us; speedup vs baseline: 1.1630x; 1.0217x over previous
//
#include <hip/hip_runtime.h>
#include <math.h>

#define N_NODES 50000
#define N_EDGES 800000
#define D_IN    128
#define H_DIM   256
#define L_LAYERS 3
#define SCAN_BLOCKS ((N_NODES + 255) / 256)   // 196
#define FILL_EBLKS ((N_EDGES + 255) / 256)    // 3125
#define DST_PER_CHUNK (N_NODES / 8)           // 6250

typedef _Float16 f16x8 __attribute__((ext_vector_type(8)));
typedef _Float16 f16x4 __attribute__((ext_vector_type(4)));
typedef float    f32x4 __attribute__((ext_vector_type(4)));

// ---------------- CSR build ----------------
// counts zeroed via hipMemsetAsync. hist's atomicAdd returns the edge's rank
// within its dst bucket -> fill is atomic-free.

__global__ __launch_bounds__(256) void hist_kernel(const int* __restrict__ dst,
                                                   int* __restrict__ counts,
                                                   int* __restrict__ rank, int e_cnt) {
    int e = blockIdx.x * 256 + threadIdx.x;
    if (e < e_cnt) rank[e] = atomicAdd(&counts[dst[e]], 1);
}

__global__ __launch_bounds__(256) void scanA_kernel(const int* __restrict__ counts,
                                                    int* __restrict__ blocksum,
                                                    float* __restrict__ dinv, int n) {
    __shared__ int s[256];
    int t = threadIdx.x;
    int i = blockIdx.x * 256 + t;
    int v = (i < n) ? counts[i] : 0;
    if (i < n) dinv[i] = rsqrtf((float)(v + 1));
    s[t] = v;
    __syncthreads();
#pragma unroll
    for (int d = 128; d > 0; d >>= 1) {
        if (t < d) s[t] += s[t + d];
        __syncthreads();
    }
    if (t == 0) blocksum[blockIdx.x] = s[0];
}

__global__ __launch_bounds__(256) void scanB_kernel(int* __restrict__ blocksum,
                                                    int* __restrict__ offsets,
                                                    int nblocks, int n, int total) {
    __shared__ int s[256];
    int t = threadIdx.x;
    int v = (t < nblocks) ? blocksum[t] : 0;
    s[t] = v;
    __syncthreads();
#pragma unroll
    for (int d = 1; d < 256; d <<= 1) {
        int x = (t >= d) ? s[t - d] : 0;
        __syncthreads();
        s[t] += x;
        __syncthreads();
    }
    if (t < nblocks) blocksum[t] = s[t] - v;
    if (t == 0) offsets[n] = total;
}

__global__ __launch_bounds__(256) void scanC_kernel(const int* __restrict__ counts,
                                                    const int* __restrict__ blocksum,
                                                    int* __restrict__ offsets, int n) {
    __shared__ int s[256];
    int t = threadIdx.x;
    int i = blockIdx.x * 256 + t;
    int v = (i < n) ? counts[i] : 0;
    s[t] = v;
    __syncthreads();
#pragma unroll
    for (int d = 1; d < 256; d <<= 1) {
        int x = (t >= d) ? s[t - d] : 0;
        __syncthreads();
        s[t] += x;
        __syncthreads();
    }
    if (i < n) offsets[i] = blocksum[blockIdx.x] + s[t] - v;
}

// fill: dst-range-chunked for write locality. A csr line's ~16 partial writes
// previously came from blocks on all 8 XCDs (non-coherent L2s -> each writes
// back a partial dirty line: 6.5x write amplification, round-0 measured).
// Chunk c (= blockIdx&7, round-robins onto XCD c) stores ONLY edges with
// dst in [c*6250,(c+1)*6250) -> csr slice ~800KB, single-XCD-written,
// L2-merged, one writeback per line. dst+rank re-read x8 (coalesced, cheap).

__global__ __launch_bounds__(256) void fill_kernel(const int* __restrict__ src,
                                                   const int* __restrict__ dst,
                                                   const int* __restrict__ offsets,
                                                   const int* __restrict__ rank,
                                                   const float* __restrict__ dinv,
                                                   int2* __restrict__ csr, int e_cnt) {
    int chunk = blockIdx.x & 7;
    int e = (blockIdx.x >> 3) * 256 + threadIdx.x;
    if (e < e_cnt) {
        int d = dst[e];
        if ((d / DST_PER_CHUNK) == chunk) {
            int pos = offsets[d] + rank[e];
            int s = src[e];
            csr[pos] = make_int2(s, __float_as_int(dinv[s]));
        }
    }
}

// ---------------- aggregation: round-0 structure (best measured) + int2 csr ----------------
// Wave = one node. lane covers cols lane*4..lane*4+3 (f16x4, 8B/lane, full 512B
// row per edge, every fetched byte used). Unroll 16/8/4/2/1. FETCH ~188MB is the
// per-XCD compulsory floor for this random gather (XCD-pin, persistence, two
// fusion variants, NT output all measured worse) — FROZEN.

__global__ __launch_bounds__(256) void aggregate_kernel(const _Float16* __restrict__ h,
                                                        const int* __restrict__ offsets,
                                                        const int2* __restrict__ csr,
                                                        const float* __restrict__ dinv,
                                                        _Float16* __restrict__ outp, int n) {
    int wave = threadIdx.x >> 6;
    int lane = threadIdx.x & 63;
    int v = blockIdx.x * 4 + wave;
    if (v >= n) return;
    int c = lane * 4;
    float dv = dinv[v];
    f16x4 self = *(const f16x4*)(h + (size_t)v * H_DIM + c);
    float ax = dv * (float)self[0];
    float ay = dv * (float)self[1];
    float az = dv * (float)self[2];
    float aw = dv * (float)self[3];

    int e  = offsets[v];
    int e1 = offsets[v + 1];

    for (; e + 15 < e1; e += 16) {
        int2 rec[16]; f16x4 r_[16];
#pragma unroll
        for (int j = 0; j < 16; ++j) rec[j] = csr[e + j];
#pragma unroll
        for (int j = 0; j < 16; ++j) r_[j] = *(const f16x4*)(h + (size_t)rec[j].x * H_DIM + c);
#pragma unroll
        for (int j = 0; j < 16; ++j) {
            float w = __int_as_float(rec[j].y);
            ax += w * (float)r_[j][0];
            ay += w * (float)r_[j][1];
            az += w * (float)r_[j][2];
            aw += w * (float)r_[j][3];
        }
    }
    if (e + 7 < e1) {
        int2 rec[8]; f16x4 r_[8];
#pragma unroll
        for (int j = 0; j < 8; ++j) rec[j] = csr[e + j];
#pragma unroll
        for (int j = 0; j < 8; ++j) r_[j] = *(const f16x4*)(h + (size_t)rec[j].x * H_DIM + c);
#pragma unroll
        for (int j = 0; j < 8; ++j) {
            float w = __int_as_float(rec[j].y);
            ax += w * (float)r_[j][0];
            ay += w * (float)r_[j][1];
            az += w * (float)r_[j][2];
            aw += w * (float)r_[j][3];
        }
        e += 8;
    }
    if (e + 3 < e1) {
        int2 rec[4]; f16x4 r_[4];
#pragma unroll
        for (int j = 0; j < 4; ++j) rec[j] = csr[e + j];
#pragma unroll
        for (int j = 0; j < 4; ++j) r_[j] = *(const f16x4*)(h + (size_t)rec[j].x * H_DIM + c);
#pragma unroll
        for (int j = 0; j < 4; ++j) {
            float w = __int_as_float(rec[j].y);
            ax += w * (float)r_[j][0];
            ay += w * (float)r_[j][1];
            az += w * (float)r_[j][2];
            aw += w * (float)r_[j][3];
        }
        e += 4;
    }
    if (e + 1 < e1) {
        int2 r0 = csr[e], r1 = csr[e + 1];
        f16x4 a = *(const f16x4*)(h + (size_t)r0.x * H_DIM + c);
        f16x4 b = *(const f16x4*)(h + (size_t)r1.x * H_DIM + c);
        float w0 = __int_as_float(r0.y), w1 = __int_as_float(r1.y);
        ax += w0 * (float)a[0] + w1 * (float)b[0];
        ay += w0 * (float)a[1] + w1 * (float)b[1];
        az += w0 * (float)a[2] + w1 * (float)b[2];
        aw += w0 * (float)a[3] + w1 * (float)b[3];
        e += 2;
    }
    if (e < e1) {
        int2 r0 = csr[e];
        f16x4 a = *(const f16x4*)(h + (size_t)r0.x * H_DIM + c);
        float w0 = __int_as_float(r0.y);
        ax += w0 * (float)a[0]; ay += w0 * (float)a[1];
        az += w0 * (float)a[2]; aw += w0 * (float)a[3];
    }
    f16x4 o;
    o[0] = (_Float16)(ax * dv);
    o[1] = (_Float16)(ay * dv);
    o[2] = (_Float16)(az * dv);
    o[3] = (_Float16)(aw * dv);
    *(f16x4*)(outp + (size_t)v * H_DIM + c) = o;
}

// ---------------- weight pre-convert: fp32 [K,256] -> frag-linear f16 hi/lo ----------------
// dst = base + (k>>5)*8192 + (n>>4)*512 + ((k&31)>>3)*128 + (n&15)*8 + (k&7)

#define WCONV_TOTAL 294912

__global__ __launch_bounds__(256) void wconv_kernel(const float* __restrict__ W_enc,
                                                    const float* __restrict__ W_g,
                                                    const float* __restrict__ W_out,
                                                    _Float16* __restrict__ whi,
                                                    _Float16* __restrict__ wlo) {
    int gid = blockIdx.x * 256 + threadIdx.x;
    if (gid >= WCONV_TOTAL) return;
    const float* src; int base, e;
    if (gid < 32768)       { src = W_enc; base = 0;      e = gid; }
    else if (gid < 229376) { src = W_g;   base = 32768;  e = gid - 32768; }
    else                   { src = W_out; base = 229376; e = gid - 229376; }
    int k = e >> 8;
    int n = e & 255;
    float x = src[e];
    _Float16 hb = (_Float16)x;
    _Float16 lb = (_Float16)(x - (float)hb);
    int dst = base + (k >> 5) * 8192 + (n >> 4) * 512 + ((k & 31) >> 3) * 128
            + (n & 15) * 8 + (k & 7);
    whi[dst] = hb;
    wlo[dst] = lb;
}

// ---------------- col-quarter MFMA GEMM (encoder + layers + head) ----------------
// ROUND-1 KNOWN-GOOD CONFIG (depth-2 A prefetch, launch_bounds(256,4)). FROZEN:
// depth-4 (r3), fusion 16/64-node (r6/r7), NT epilogue (r8) all measured worse.

template <int KC, int AMODE, int OUT16>
__global__ __launch_bounds__(256, 4) void mfma_gemm(const float* __restrict__ Af,
                                                    const _Float16* __restrict__ A16,
                                                    const _Float16* __restrict__ WhG,
                                                    const _Float16* __restrict__ WlG,
                                                    const float* __restrict__ bias,
                                                    float* __restrict__ Cf,
                                                    _Float16* __restrict__ Ch,
                                                    int n, int relu) {
    constexpr int K   = KC * 32;
    constexpr int PKC = (KC >= 8) ? 4 : KC;   // kc per staging phase
    constexpr int NPH = KC / PKC;
    __shared__ _Float16 Wlds[PKC * 2 * 2048]; // [pk][hi/lo][c(4)][lane(64)][j(8)] = 32 KB

    int t = threadIdx.x;
    int w = t >> 6;
    int lane = t & 63;
    int q  = blockIdx.x >> 8;
    int rt = blockIdx.x & 255;
    if (rt * 256 >= n) return;
    int colbase = q * 64;
    int mrow = lane & 15;
    int koct = (lane >> 4) * 8;
    int rbase = rt * 256 + w * 64;

    int rows[4];
#pragma unroll
    for (int mt = 0; mt < 4; ++mt) {
        int r = rbase + mt * 16 + mrow;
        rows[mt] = (r < n) ? r : (n - 1);     // clamp: dup rows, never stored
    }

    f32x4 acc[4][4];
#pragma unroll
    for (int mt = 0; mt < 4; ++mt)
#pragma unroll
        for (int c = 0; c < 4; ++c)
            acc[mt][c] = (f32x4)(0.0f);

    // ---- A register pipeline ----
    f16x8 a16p[2][4];                 // AMODE 1: depth-2
    float4 af0[4], af1[4];            // AMODE 0: depth-1
    if (AMODE == 1) {
#pragma unroll
        for (int mt = 0; mt < 4; ++mt) {
            a16p[0][mt] = *(const f16x8*)(A16 + (size_t)rows[mt] * K + koct);
            a16p[1][mt] = *(const f16x8*)(A16 + (size_t)rows[mt] * K + 32 + koct);
        }
    } else {
#pragma unroll
        for (int mt = 0; mt < 4; ++mt) {
            const float* p = Af + (size_t)rows[mt] * K + koct;
            af0[mt] = *(const float4*)p;
            af1[mt] = *(const float4*)(p + 4);
        }
    }

#pragma unroll
    for (int ph = 0; ph < NPH; ++ph) {
        if (ph) __syncthreads();              // all waves done reading previous phase
#pragma unroll
        for (int pk = 0; pk < PKC; ++pk) {
            int kc = ph * PKC + pk;
            __builtin_amdgcn_global_load_lds(
                (const __attribute__((address_space(1))) unsigned int*)(WhG + (size_t)kc * 8192 + q * 2048 + t * 8),
                (__attribute__((address_space(3))) unsigned int*)(&Wlds[(pk * 2 + 0) * 2048 + t * 8]), 16, 0, 0);
            __builtin_amdgcn_global_load_lds(
                (const __attribute__((address_space(1))) unsigned int*)(WlG + (size_t)kc * 8192 + q * 2048 + t * 8),
                (__attribute__((address_space(3))) unsigned int*)(&Wlds[(pk * 2 + 1) * 2048 + t * 8]), 16, 0, 0);
        }
        __syncthreads();

#pragma unroll
        for (int pk = 0; pk < PKC; ++pk) {
            int kc = ph * PKC + pk;
            f16x8 ah[4], al[4];
            if (AMODE == 0) {
#pragma unroll
                for (int mt = 0; mt < 4; ++mt) {
                    float4 c0 = af0[mt], c1 = af1[mt];
                    if (kc + 1 < KC) {
                        const float* p = Af + (size_t)rows[mt] * K + (kc + 1) * 32 + koct;
                        af0[mt] = *(const float4*)p;
                        af1[mt] = *(const float4*)(p + 4);
                    }
                    float xs[8] = {c0.x, c0.y, c0.z, c0.w, c1.x, c1.y, c1.z, c1.w};
                    f16x8 H, L;
#pragma unroll
                    for (int j = 0; j < 8; ++j) {
                        _Float16 hb = (_Float16)xs[j];
                        H[j] = hb;
                        L[j] = (_Float16)(xs[j] - (float)hb);
                    }
                    ah[mt] = H;
                    al[mt] = L;
                }
            }

#pragma unroll
            for (int c = 0; c < 4; ++c) {
                f16x8 bh = *(const f16x8*)&Wlds[(pk * 2 + 0) * 2048 + c * 512 + lane * 8];
                f16x8 bl = *(const f16x8*)&Wlds[(pk * 2 + 1) * 2048 + c * 512 + lane * 8];
#pragma unroll
                for (int mt = 0; mt < 4; ++mt) {
                    if (AMODE == 1) {
                        f16x8 a = a16p[kc & 1][mt];
                        acc[mt][c] = __builtin_amdgcn_mfma_f32_16x16x32_f16(a, bh, acc[mt][c], 0, 0, 0);
                        acc[mt][c] = __builtin_amdgcn_mfma_f32_16x16x32_f16(a, bl, acc[mt][c], 0, 0, 0);
                    } else {
                        acc[mt][c] = __builtin_amdgcn_mfma_f32_16x16x32_f16(ah[mt], bh, acc[mt][c], 0, 0, 0);
                        acc[mt][c] = __builtin_amdgcn_mfma_f32_16x16x32_f16(ah[mt], bl, acc[mt][c], 0, 0, 0);
                        acc[mt][c] = __builtin_amdgcn_mfma_f32_16x16x32_f16(al[mt], bh, acc[mt][c], 0, 0, 0);
                    }
                }
            }

            if (AMODE == 1 && kc + 2 < KC) {
#pragma unroll
                for (int mt = 0; mt < 4; ++mt)
                    a16p[kc & 1][mt] = *(const f16x8*)(A16 + (size_t)rows[mt] * K + (kc + 2) * 32 + koct);
            }
        }
    }

    // ---- epilogue: C/D layout col=lane&15, row=(lane>>4)*4+reg ----
    int colq = lane & 15;
    int rowq = (lane >> 4) * 4;
#pragma unroll
    for (int c = 0; c < 4; ++c) {
        int col = colbase + c * 16 + colq;
        float b = bias[col];
#pragma unroll
        for (int mt = 0; mt < 4; ++mt) {
            int rb = rbase + mt * 16 + rowq;
#pragma unroll
            for (int r = 0; r < 4; ++r) {
                int row = rb + r;
                if (row < n) {
                    float v = acc[mt][c][r] + b;
                    if (relu) v = fmaxf(v, 0.f);
                    if (OUT16) Ch[(size_t)row * H_DIM + col] = (_Float16)v;
                    else       Cf[(size_t)row * H_DIM + col] = v;
                }
            }
        }
    }
}

// ---------------- launch ----------------

extern "C" void kernel_launch(void* const* d_in, const int* in_sizes, int n_in,
                              void* d_out, int out_size, void* d_ws, size_t ws_size,
                              hipStream_t stream) {
    const float* x     = (const float*)d_in[0];
    const int*   ei    = (const int*)d_in[1];
    const float* W_enc = (const float*)d_in[3];
    const float* b_enc = (const float*)d_in[4];
    const float* W_g   = (const float*)d_in[5];
    const float* b_g   = (const float*)d_in[6];
    const float* W_out = (const float*)d_in[7];
    const float* b_out = (const float*)d_in[8];
    float* out = (float*)d_out;

    char* ws = (char*)d_ws;
    size_t off = 0;
    auto alloc = [&](size_t bytes) -> void* {
        void* p = ws + off;
        off = (off + bytes + 255) & ~(size_t)255;
        return p;
    };
    int*       counts   = (int*)alloc((size_t)N_NODES * 4);
    int*       offsets  = (int*)alloc((size_t)(N_NODES + 1) * 4);
    float*     dinv     = (float*)alloc((size_t)N_NODES * 4);
    int*       blocksum = (int*)alloc((size_t)SCAN_BLOCKS * 4);
    int*       rank     = (int*)alloc((size_t)N_EDGES * 4);
    int2*      csr      = (int2*)alloc((size_t)N_EDGES * 8);
    _Float16*  h16      = (_Float16*)alloc((size_t)N_NODES * H_DIM * 2);
    _Float16*  agg16    = (_Float16*)alloc((size_t)N_NODES * H_DIM * 2);
    _Float16*  whi      = (_Float16*)alloc((size_t)WCONV_TOTAL * 2);
    _Float16*  wlo      = (_Float16*)alloc((size_t)WCONV_TOTAL * 2);

    const int* src = ei;
    const int* dst = ei + N_EDGES;

    hipMemsetAsync(counts, 0, (size_t)N_NODES * 4, stream);
    hist_kernel<<<(N_EDGES + 255) / 256, 256, 0, stream>>>(dst, counts, rank, N_EDGES);
    scanA_kernel<<<SCAN_BLOCKS, 256, 0, stream>>>(counts, blocksum, dinv, N_NODES);
    scanB_kernel<<<1, 256, 0, stream>>>(blocksum, offsets, SCAN_BLOCKS, N_NODES, N_EDGES);
    scanC_kernel<<<SCAN_BLOCKS, 256, 0, stream>>>(counts, blocksum, offsets, N_NODES);
    // dst-range-chunked fill: grid = 8 chunks x 3125 edge-blocks
    fill_kernel<<<8 * FILL_EBLKS, 256, 0, stream>>>(src, dst, offsets, rank, dinv,
                                                    csr, N_EDGES);
    wconv_kernel<<<(WCONV_TOTAL + 255) / 256, 256, 0, stream>>>(W_enc, W_g, W_out, whi, wlo);

    // encoder: h1 = relu(x @ W_enc + b_enc)  — KC=4 (K=128), fp32 A inline-split
    mfma_gemm<4, 0, 1><<<1024, 256, 0, stream>>>(x, (const _Float16*)nullptr,
                                                 whi, wlo, b_enc,
                                                 (float*)nullptr, h16, N_NODES, 1);
    // 3 GCN layers
    for (int l = 0; l < L_LAYERS; ++l) {
        aggregate_kernel<<<N_NODES / 4, 256, 0, stream>>>(h16, offsets, csr, dinv,
                                                          agg16, N_NODES);
        mfma_gemm<8, 1, 1><<<1024, 256, 0, stream>>>((const float*)nullptr, agg16,
                                                     whi + 32768 + (size_t)l * 65536,
                                                     wlo + 32768 + (size_t)l * 65536,
                                                     b_g + (size_t)l * H_DIM,
                                                     (float*)nullptr, h16, N_NODES, 1);
    }
    // output head (no relu), f16 A, fp32 out
    mfma_gemm<8, 1, 0><<<1024, 256, 0, stream>>>((const float*)nullptr, h16,
                                                 whi + 229376, wlo + 229376, b_out,
                                                 out, (_Float16*)nullptr, N_NODES, 0);
}

// Round 10
// 491.880 us; speedup vs baseline: 1.1806x; 1.0151x over previous
//
#include <hip/hip_runtime.h>
#include <math.h>

#define N_NODES 50000
#define N_EDGES 800000
#define D_IN    128
#define H_DIM   256
#define L_LAYERS 3
#define BUCKET  64            // fixed csr bucket stride; P(deg>=64) ~ 2e-19/node

typedef _Float16 f16x8 __attribute__((ext_vector_type(8)));
typedef _Float16 f16x4 __attribute__((ext_vector_type(4)));
typedef float    f32x4 __attribute__((ext_vector_type(4)));

// ---------------- CSR build (bucket layout, no scans) ----------------
// counts zeroed via hipMemsetAsync. hist's atomicAdd returns the edge's rank
// within its dst bucket. pos = dst*64 + rank -> no prefix-sum needed at all.

__global__ __launch_bounds__(256) void hist_kernel(const int* __restrict__ dst,
                                                   int* __restrict__ counts,
                                                   int* __restrict__ rank, int e_cnt) {
    int e = blockIdx.x * 256 + threadIdx.x;
    if (e < e_cnt) rank[e] = atomicAdd(&counts[dst[e]], 1);
}

__global__ __launch_bounds__(256) void dinv_kernel(const int* __restrict__ counts,
                                                   float* __restrict__ dinv, int n) {
    int i = blockIdx.x * 256 + threadIdx.x;
    if (i < n) dinv[i] = rsqrtf((float)(counts[i] + 1));
}

// fill: atomic-free, ONE scattered 8B record per edge (src, dinv[src]) at
// bucket-fixed position. No offsets read.

__global__ __launch_bounds__(256) void fill_kernel(const int* __restrict__ src,
                                                   const int* __restrict__ dst,
                                                   const int* __restrict__ rank,
                                                   const float* __restrict__ dinv,
                                                   int2* __restrict__ csr, int e_cnt) {
    int e = blockIdx.x * 256 + threadIdx.x;
    if (e < e_cnt) {
        int d = dst[e];
        int pos = d * BUCKET + rank[e];
        int s = src[e];
        csr[pos] = make_int2(s, __float_as_int(dinv[s]));
    }
}

// ---------------- aggregation: round-0 structure (best measured) + bucket csr ----------------
// Wave = one node. lane covers cols lane*4..lane*4+3 (f16x4, 8B/lane, full 512B
// row per edge, every fetched byte used). Unroll 16/8/4/2/1. FETCH ~188MB is the
// per-XCD compulsory floor for this random gather (6 restructures all measured
// worse or equal) — gather loop FROZEN. Bounds from counts[v], base = v*64.

__global__ __launch_bounds__(256) void aggregate_kernel(const _Float16* __restrict__ h,
                                                        const int* __restrict__ counts,
                                                        const int2* __restrict__ csr,
                                                        const float* __restrict__ dinv,
                                                        _Float16* __restrict__ outp, int n) {
    int wave = threadIdx.x >> 6;
    int lane = threadIdx.x & 63;
    int v = blockIdx.x * 4 + wave;
    if (v >= n) return;
    int c = lane * 4;
    float dv = dinv[v];
    f16x4 self = *(const f16x4*)(h + (size_t)v * H_DIM + c);
    float ax = dv * (float)self[0];
    float ay = dv * (float)self[1];
    float az = dv * (float)self[2];
    float aw = dv * (float)self[3];

    int e  = v * BUCKET;
    int e1 = e + counts[v];

    for (; e + 15 < e1; e += 16) {
        int2 rec[16]; f16x4 r_[16];
#pragma unroll
        for (int j = 0; j < 16; ++j) rec[j] = csr[e + j];
#pragma unroll
        for (int j = 0; j < 16; ++j) r_[j] = *(const f16x4*)(h + (size_t)rec[j].x * H_DIM + c);
#pragma unroll
        for (int j = 0; j < 16; ++j) {
            float w = __int_as_float(rec[j].y);
            ax += w * (float)r_[j][0];
            ay += w * (float)r_[j][1];
            az += w * (float)r_[j][2];
            aw += w * (float)r_[j][3];
        }
    }
    if (e + 7 < e1) {
        int2 rec[8]; f16x4 r_[8];
#pragma unroll
        for (int j = 0; j < 8; ++j) rec[j] = csr[e + j];
#pragma unroll
        for (int j = 0; j < 8; ++j) r_[j] = *(const f16x4*)(h + (size_t)rec[j].x * H_DIM + c);
#pragma unroll
        for (int j = 0; j < 8; ++j) {
            float w = __int_as_float(rec[j].y);
            ax += w * (float)r_[j][0];
            ay += w * (float)r_[j][1];
            az += w * (float)r_[j][2];
            aw += w * (float)r_[j][3];
        }
        e += 8;
    }
    if (e + 3 < e1) {
        int2 rec[4]; f16x4 r_[4];
#pragma unroll
        for (int j = 0; j < 4; ++j) rec[j] = csr[e + j];
#pragma unroll
        for (int j = 0; j < 4; ++j) r_[j] = *(const f16x4*)(h + (size_t)rec[j].x * H_DIM + c);
#pragma unroll
        for (int j = 0; j < 4; ++j) {
            float w = __int_as_float(rec[j].y);
            ax += w * (float)r_[j][0];
            ay += w * (float)r_[j][1];
            az += w * (float)r_[j][2];
            aw += w * (float)r_[j][3];
        }
        e += 4;
    }
    if (e + 1 < e1) {
        int2 r0 = csr[e], r1 = csr[e + 1];
        f16x4 a = *(const f16x4*)(h + (size_t)r0.x * H_DIM + c);
        f16x4 b = *(const f16x4*)(h + (size_t)r1.x * H_DIM + c);
        float w0 = __int_as_float(r0.y), w1 = __int_as_float(r1.y);
        ax += w0 * (float)a[0] + w1 * (float)b[0];
        ay += w0 * (float)a[1] + w1 * (float)b[1];
        az += w0 * (float)a[2] + w1 * (float)b[2];
        aw += w0 * (float)a[3] + w1 * (float)b[3];
        e += 2;
    }
    if (e < e1) {
        int2 r0 = csr[e];
        f16x4 a = *(const f16x4*)(h + (size_t)r0.x * H_DIM + c);
        float w0 = __int_as_float(r0.y);
        ax += w0 * (float)a[0]; ay += w0 * (float)a[1];
        az += w0 * (float)a[2]; aw += w0 * (float)a[3];
    }
    f16x4 o;
    o[0] = (_Float16)(ax * dv);
    o[1] = (_Float16)(ay * dv);
    o[2] = (_Float16)(az * dv);
    o[3] = (_Float16)(aw * dv);
    *(f16x4*)(outp + (size_t)v * H_DIM + c) = o;
}

// ---------------- weight pre-convert: fp32 [K,256] -> frag-linear f16 hi/lo ----------------
// dst = base + (k>>5)*8192 + (n>>4)*512 + ((k&31)>>3)*128 + (n&15)*8 + (k&7)

#define WCONV_TOTAL 294912

__global__ __launch_bounds__(256) void wconv_kernel(const float* __restrict__ W_enc,
                                                    const float* __restrict__ W_g,
                                                    const float* __restrict__ W_out,
                                                    _Float16* __restrict__ whi,
                                                    _Float16* __restrict__ wlo) {
    int gid = blockIdx.x * 256 + threadIdx.x;
    if (gid >= WCONV_TOTAL) return;
    const float* src; int base, e;
    if (gid < 32768)       { src = W_enc; base = 0;      e = gid; }
    else if (gid < 229376) { src = W_g;   base = 32768;  e = gid - 32768; }
    else                   { src = W_out; base = 229376; e = gid - 229376; }
    int k = e >> 8;
    int n = e & 255;
    float x = src[e];
    _Float16 hb = (_Float16)x;
    _Float16 lb = (_Float16)(x - (float)hb);
    int dst = base + (k >> 5) * 8192 + (n >> 4) * 512 + ((k & 31) >> 3) * 128
            + (n & 15) * 8 + (k & 7);
    whi[dst] = hb;
    wlo[dst] = lb;
}

// ---------------- col-quarter MFMA GEMM (encoder + layers + head) ----------------
// ROUND-1 KNOWN-GOOD CONFIG (depth-2 A prefetch, launch_bounds(256,4)). FROZEN:
// depth-4 (r3), fusion 16/64-node (r6/r7), NT epilogue (r8) all measured worse.

template <int KC, int AMODE, int OUT16>
__global__ __launch_bounds__(256, 4) void mfma_gemm(const float* __restrict__ Af,
                                                    const _Float16* __restrict__ A16,
                                                    const _Float16* __restrict__ WhG,
                                                    const _Float16* __restrict__ WlG,
                                                    const float* __restrict__ bias,
                                                    float* __restrict__ Cf,
                                                    _Float16* __restrict__ Ch,
                                                    int n, int relu) {
    constexpr int K   = KC * 32;
    constexpr int PKC = (KC >= 8) ? 4 : KC;   // kc per staging phase
    constexpr int NPH = KC / PKC;
    __shared__ _Float16 Wlds[PKC * 2 * 2048]; // [pk][hi/lo][c(4)][lane(64)][j(8)] = 32 KB

    int t = threadIdx.x;
    int w = t >> 6;
    int lane = t & 63;
    int q  = blockIdx.x >> 8;
    int rt = blockIdx.x & 255;
    if (rt * 256 >= n) return;
    int colbase = q * 64;
    int mrow = lane & 15;
    int koct = (lane >> 4) * 8;
    int rbase = rt * 256 + w * 64;

    int rows[4];
#pragma unroll
    for (int mt = 0; mt < 4; ++mt) {
        int r = rbase + mt * 16 + mrow;
        rows[mt] = (r < n) ? r : (n - 1);     // clamp: dup rows, never stored
    }

    f32x4 acc[4][4];
#pragma unroll
    for (int mt = 0; mt < 4; ++mt)
#pragma unroll
        for (int c = 0; c < 4; ++c)
            acc[mt][c] = (f32x4)(0.0f);

    // ---- A register pipeline ----
    f16x8 a16p[2][4];                 // AMODE 1: depth-2
    float4 af0[4], af1[4];            // AMODE 0: depth-1
    if (AMODE == 1) {
#pragma unroll
        for (int mt = 0; mt < 4; ++mt) {
            a16p[0][mt] = *(const f16x8*)(A16 + (size_t)rows[mt] * K + koct);
            a16p[1][mt] = *(const f16x8*)(A16 + (size_t)rows[mt] * K + 32 + koct);
        }
    } else {
#pragma unroll
        for (int mt = 0; mt < 4; ++mt) {
            const float* p = Af + (size_t)rows[mt] * K + koct;
            af0[mt] = *(const float4*)p;
            af1[mt] = *(const float4*)(p + 4);
        }
    }

#pragma unroll
    for (int ph = 0; ph < NPH; ++ph) {
        if (ph) __syncthreads();              // all waves done reading previous phase
#pragma unroll
        for (int pk = 0; pk < PKC; ++pk) {
            int kc = ph * PKC + pk;
            __builtin_amdgcn_global_load_lds(
                (const __attribute__((address_space(1))) unsigned int*)(WhG + (size_t)kc * 8192 + q * 2048 + t * 8),
                (__attribute__((address_space(3))) unsigned int*)(&Wlds[(pk * 2 + 0) * 2048 + t * 8]), 16, 0, 0);
            __builtin_amdgcn_global_load_lds(
                (const __attribute__((address_space(1))) unsigned int*)(WlG + (size_t)kc * 8192 + q * 2048 + t * 8),
                (__attribute__((address_space(3))) unsigned int*)(&Wlds[(pk * 2 + 1) * 2048 + t * 8]), 16, 0, 0);
        }
        __syncthreads();

#pragma unroll
        for (int pk = 0; pk < PKC; ++pk) {
            int kc = ph * PKC + pk;
            f16x8 ah[4], al[4];
            if (AMODE == 0) {
#pragma unroll
                for (int mt = 0; mt < 4; ++mt) {
                    float4 c0 = af0[mt], c1 = af1[mt];
                    if (kc + 1 < KC) {
                        const float* p = Af + (size_t)rows[mt] * K + (kc + 1) * 32 + koct;
                        af0[mt] = *(const float4*)p;
                        af1[mt] = *(const float4*)(p + 4);
                    }
                    float xs[8] = {c0.x, c0.y, c0.z, c0.w, c1.x, c1.y, c1.z, c1.w};
                    f16x8 H, L;
#pragma unroll
                    for (int j = 0; j < 8; ++j) {
                        _Float16 hb = (_Float16)xs[j];
                        H[j] = hb;
                        L[j] = (_Float16)(xs[j] - (float)hb);
                    }
                    ah[mt] = H;
                    al[mt] = L;
                }
            }

#pragma unroll
            for (int c = 0; c < 4; ++c) {
                f16x8 bh = *(const f16x8*)&Wlds[(pk * 2 + 0) * 2048 + c * 512 + lane * 8];
                f16x8 bl = *(const f16x8*)&Wlds[(pk * 2 + 1) * 2048 + c * 512 + lane * 8];
#pragma unroll
                for (int mt = 0; mt < 4; ++mt) {
                    if (AMODE == 1) {
                        f16x8 a = a16p[kc & 1][mt];
                        acc[mt][c] = __builtin_amdgcn_mfma_f32_16x16x32_f16(a, bh, acc[mt][c], 0, 0, 0);
                        acc[mt][c] = __builtin_amdgcn_mfma_f32_16x16x32_f16(a, bl, acc[mt][c], 0, 0, 0);
                    } else {
                        acc[mt][c] = __builtin_amdgcn_mfma_f32_16x16x32_f16(ah[mt], bh, acc[mt][c], 0, 0, 0);
                        acc[mt][c] = __builtin_amdgcn_mfma_f32_16x16x32_f16(ah[mt], bl, acc[mt][c], 0, 0, 0);
                        acc[mt][c] = __builtin_amdgcn_mfma_f32_16x16x32_f16(al[mt], bh, acc[mt][c], 0, 0, 0);
                    }
                }
            }

            if (AMODE == 1 && kc + 2 < KC) {
#pragma unroll
                for (int mt = 0; mt < 4; ++mt)
                    a16p[kc & 1][mt] = *(const f16x8*)(A16 + (size_t)rows[mt] * K + (kc + 2) * 32 + koct);
            }
        }
    }

    // ---- epilogue: C/D layout col=lane&15, row=(lane>>4)*4+reg ----
    int colq = lane & 15;
    int rowq = (lane >> 4) * 4;
#pragma unroll
    for (int c = 0; c < 4; ++c) {
        int col = colbase + c * 16 + colq;
        float b = bias[col];
#pragma unroll
        for (int mt = 0; mt < 4; ++mt) {
            int rb = rbase + mt * 16 + rowq;
#pragma unroll
            for (int r = 0; r < 4; ++r) {
                int row = rb + r;
                if (row < n) {
                    float v = acc[mt][c][r] + b;
                    if (relu) v = fmaxf(v, 0.f);
                    if (OUT16) Ch[(size_t)row * H_DIM + col] = (_Float16)v;
                    else       Cf[(size_t)row * H_DIM + col] = v;
                }
            }
        }
    }
}

// ---------------- launch ----------------

extern "C" void kernel_launch(void* const* d_in, const int* in_sizes, int n_in,
                              void* d_out, int out_size, void* d_ws, size_t ws_size,
                              hipStream_t stream) {
    const float* x     = (const float*)d_in[0];
    const int*   ei    = (const int*)d_in[1];
    const float* W_enc = (const float*)d_in[3];
    const float* b_enc = (const float*)d_in[4];
    const float* W_g   = (const float*)d_in[5];
    const float* b_g   = (const float*)d_in[6];
    const float* W_out = (const float*)d_in[7];
    const float* b_out = (const float*)d_in[8];
    float* out = (float*)d_out;

    char* ws = (char*)d_ws;
    size_t off = 0;
    auto alloc = [&](size_t bytes) -> void* {
        void* p = ws + off;
        off = (off + bytes + 255) & ~(size_t)255;
        return p;
    };
    int*       counts   = (int*)alloc((size_t)N_NODES * 4);
    float*     dinv     = (float*)alloc((size_t)N_NODES * 4);
    int*       rank     = (int*)alloc((size_t)N_EDGES * 4);
    int2*      csr      = (int2*)alloc((size_t)N_NODES * BUCKET * 8);
    _Float16*  h16      = (_Float16*)alloc((size_t)N_NODES * H_DIM * 2);
    _Float16*  agg16    = (_Float16*)alloc((size_t)N_NODES * H_DIM * 2);
    _Float16*  whi      = (_Float16*)alloc((size_t)WCONV_TOTAL * 2);
    _Float16*  wlo      = (_Float16*)alloc((size_t)WCONV_TOTAL * 2);

    const int* src = ei;
    const int* dst = ei + N_EDGES;

    hipMemsetAsync(counts, 0, (size_t)N_NODES * 4, stream);
    hist_kernel<<<(N_EDGES + 255) / 256, 256, 0, stream>>>(dst, counts, rank, N_EDGES);
    dinv_kernel<<<(N_NODES + 255) / 256, 256, 0, stream>>>(counts, dinv, N_NODES);
    fill_kernel<<<(N_EDGES + 255) / 256, 256, 0, stream>>>(src, dst, rank, dinv,
                                                           csr, N_EDGES);
    wconv_kernel<<<(WCONV_TOTAL + 255) / 256, 256, 0, stream>>>(W_enc, W_g, W_out, whi, wlo);

    // encoder: h1 = relu(x @ W_enc + b_enc)  — KC=4 (K=128), fp32 A inline-split
    mfma_gemm<4, 0, 1><<<1024, 256, 0, stream>>>(x, (const _Float16*)nullptr,
                                                 whi, wlo, b_enc,
                                                 (float*)nullptr, h16, N_NODES, 1);
    // 3 GCN layers
    for (int l = 0; l < L_LAYERS; ++l) {
        aggregate_kernel<<<N_NODES / 4, 256, 0, stream>>>(h16, counts, csr, dinv,
                                                          agg16, N_NODES);
        mfma_gemm<8, 1, 1><<<1024, 256, 0, stream>>>((const float*)nullptr, agg16,
                                                     whi + 32768 + (size_t)l * 65536,
                                                     wlo + 32768 + (size_t)l * 65536,
                                                     b_g + (size_t)l * H_DIM,
                                                     (float*)nullptr, h16, N_NODES, 1);
    }
    // output head (no relu), f16 A, fp32 out
    mfma_gemm<8, 1, 0><<<1024, 256, 0, stream>>>((const float*)nullptr, h16,
                                                 whi + 229376, wlo + 229376, b_out,
                                                 out, (_Float16*)nullptr, N_NODES, 0);
}

// Round 11
// 487.521 us; speedup vs baseline: 1.1912x; 1.0089x over previous
//
#include <hip/hip_runtime.h>
#include <math.h>

#define N_NODES 50000
#define N_EDGES 800000
#define D_IN    128
#define H_DIM   256
#define L_LAYERS 3
#define BUCKET  64            // fixed csr bucket stride; P(deg>=64) ~ 2e-19/node

typedef _Float16 f16x8 __attribute__((ext_vector_type(8)));
typedef _Float16 f16x4 __attribute__((ext_vector_type(4)));
typedef float    f32x4 __attribute__((ext_vector_type(4)));

// ---------------- CSR build (bucket layout, no scans, no dinv table) ----------------
// counts zeroed via hipMemsetAsync. hist's atomicAdd yields the edge's rank;
// hist emits the FINAL csr position pos = dst*64 + rank (dst already in reg).
// dinv is never materialized: consumers compute rsqrt(counts+1) on the fly
// (counts is a 200KB L2-hot table; rsqrt is 1 VALU op).

__global__ __launch_bounds__(256) void hist_kernel(const int* __restrict__ dst,
                                                   int* __restrict__ counts,
                                                   int* __restrict__ pos, int e_cnt) {
    int e = blockIdx.x * 256 + threadIdx.x;
    if (e < e_cnt) {
        int d = dst[e];
        int r = atomicAdd(&counts[d], 1);
        pos[e] = d * BUCKET + r;
    }
}

// fill: atomic-free, reads only src+pos (6.4MB coalesced) + counts gather
// (L2-hot), ONE scattered 8B record per edge (src, dinv[src]).

__global__ __launch_bounds__(256) void fill_kernel(const int* __restrict__ src,
                                                   const int* __restrict__ pos,
                                                   const int* __restrict__ counts,
                                                   int2* __restrict__ csr, int e_cnt) {
    int e = blockIdx.x * 256 + threadIdx.x;
    if (e < e_cnt) {
        int s = src[e];
        float w = rsqrtf((float)(counts[s] + 1));
        csr[pos[e]] = make_int2(s, __float_as_int(w));
    }
}

// ---------------- aggregation: round-0 structure (best measured) + bucket csr ----------------
// Wave = one node. lane covers cols lane*4..lane*4+3 (f16x4, 8B/lane, full 512B
// row per edge, every fetched byte used). Unroll 16/8/4/2/1. FETCH ~188MB and
// ~60.5us are invariant across 7 restructures -> random-64B-gather floor, FROZEN.
// dv computed from counts[v] (already loaded for the loop bound).

__global__ __launch_bounds__(256) void aggregate_kernel(const _Float16* __restrict__ h,
                                                        const int* __restrict__ counts,
                                                        const int2* __restrict__ csr,
                                                        _Float16* __restrict__ outp, int n) {
    int wave = threadIdx.x >> 6;
    int lane = threadIdx.x & 63;
    int v = blockIdx.x * 4 + wave;
    if (v >= n) return;
    int c = lane * 4;
    int cnt = counts[v];
    float dv = rsqrtf((float)(cnt + 1));
    f16x4 self = *(const f16x4*)(h + (size_t)v * H_DIM + c);
    float ax = dv * (float)self[0];
    float ay = dv * (float)self[1];
    float az = dv * (float)self[2];
    float aw = dv * (float)self[3];

    int e  = v * BUCKET;
    int e1 = e + cnt;

    for (; e + 15 < e1; e += 16) {
        int2 rec[16]; f16x4 r_[16];
#pragma unroll
        for (int j = 0; j < 16; ++j) rec[j] = csr[e + j];
#pragma unroll
        for (int j = 0; j < 16; ++j) r_[j] = *(const f16x4*)(h + (size_t)rec[j].x * H_DIM + c);
#pragma unroll
        for (int j = 0; j < 16; ++j) {
            float w = __int_as_float(rec[j].y);
            ax += w * (float)r_[j][0];
            ay += w * (float)r_[j][1];
            az += w * (float)r_[j][2];
            aw += w * (float)r_[j][3];
        }
    }
    if (e + 7 < e1) {
        int2 rec[8]; f16x4 r_[8];
#pragma unroll
        for (int j = 0; j < 8; ++j) rec[j] = csr[e + j];
#pragma unroll
        for (int j = 0; j < 8; ++j) r_[j] = *(const f16x4*)(h + (size_t)rec[j].x * H_DIM + c);
#pragma unroll
        for (int j = 0; j < 8; ++j) {
            float w = __int_as_float(rec[j].y);
            ax += w * (float)r_[j][0];
            ay += w * (float)r_[j][1];
            az += w * (float)r_[j][2];
            aw += w * (float)r_[j][3];
        }
        e += 8;
    }
    if (e + 3 < e1) {
        int2 rec[4]; f16x4 r_[4];
#pragma unroll
        for (int j = 0; j < 4; ++j) rec[j] = csr[e + j];
#pragma unroll
        for (int j = 0; j < 4; ++j) r_[j] = *(const f16x4*)(h + (size_t)rec[j].x * H_DIM + c);
#pragma unroll
        for (int j = 0; j < 4; ++j) {
            float w = __int_as_float(rec[j].y);
            ax += w * (float)r_[j][0];
            ay += w * (float)r_[j][1];
            az += w * (float)r_[j][2];
            aw += w * (float)r_[j][3];
        }
        e += 4;
    }
    if (e + 1 < e1) {
        int2 r0 = csr[e], r1 = csr[e + 1];
        f16x4 a = *(const f16x4*)(h + (size_t)r0.x * H_DIM + c);
        f16x4 b = *(const f16x4*)(h + (size_t)r1.x * H_DIM + c);
        float w0 = __int_as_float(r0.y), w1 = __int_as_float(r1.y);
        ax += w0 * (float)a[0] + w1 * (float)b[0];
        ay += w0 * (float)a[1] + w1 * (float)b[1];
        az += w0 * (float)a[2] + w1 * (float)b[2];
        aw += w0 * (float)a[3] + w1 * (float)b[3];
        e += 2;
    }
    if (e < e1) {
        int2 r0 = csr[e];
        f16x4 a = *(const f16x4*)(h + (size_t)r0.x * H_DIM + c);
        float w0 = __int_as_float(r0.y);
        ax += w0 * (float)a[0]; ay += w0 * (float)a[1];
        az += w0 * (float)a[2]; aw += w0 * (float)a[3];
    }
    f16x4 o;
    o[0] = (_Float16)(ax * dv);
    o[1] = (_Float16)(ay * dv);
    o[2] = (_Float16)(az * dv);
    o[3] = (_Float16)(aw * dv);
    *(f16x4*)(outp + (size_t)v * H_DIM + c) = o;
}

// ---------------- weight pre-convert: fp32 [K,256] -> frag-linear f16 hi/lo ----------------
// dst = base + (k>>5)*8192 + (n>>4)*512 + ((k&31)>>3)*128 + (n&15)*8 + (k&7)

#define WCONV_TOTAL 294912

__global__ __launch_bounds__(256) void wconv_kernel(const float* __restrict__ W_enc,
                                                    const float* __restrict__ W_g,
                                                    const float* __restrict__ W_out,
                                                    _Float16* __restrict__ whi,
                                                    _Float16* __restrict__ wlo) {
    int gid = blockIdx.x * 256 + threadIdx.x;
    if (gid >= WCONV_TOTAL) return;
    const float* src; int base, e;
    if (gid < 32768)       { src = W_enc; base = 0;      e = gid; }
    else if (gid < 229376) { src = W_g;   base = 32768;  e = gid - 32768; }
    else                   { src = W_out; base = 229376; e = gid - 229376; }
    int k = e >> 8;
    int n = e & 255;
    float x = src[e];
    _Float16 hb = (_Float16)x;
    _Float16 lb = (_Float16)(x - (float)hb);
    int dst = base + (k >> 5) * 8192 + (n >> 4) * 512 + ((k & 31) >> 3) * 128
            + (n & 15) * 8 + (k & 7);
    whi[dst] = hb;
    wlo[dst] = lb;
}

// ---------------- col-quarter MFMA GEMM (encoder + layers + head) ----------------
// ROUND-1 KNOWN-GOOD CONFIG (depth-2 A prefetch, launch_bounds(256,4)). FROZEN:
// depth-4 (r3), fusion 16/64-node (r6/r7), NT epilogue (r8) all measured worse.

template <int KC, int AMODE, int OUT16>
__global__ __launch_bounds__(256, 4) void mfma_gemm(const float* __restrict__ Af,
                                                    const _Float16* __restrict__ A16,
                                                    const _Float16* __restrict__ WhG,
                                                    const _Float16* __restrict__ WlG,
                                                    const float* __restrict__ bias,
                                                    float* __restrict__ Cf,
                                                    _Float16* __restrict__ Ch,
                                                    int n, int relu) {
    constexpr int K   = KC * 32;
    constexpr int PKC = (KC >= 8) ? 4 : KC;   // kc per staging phase
    constexpr int NPH = KC / PKC;
    __shared__ _Float16 Wlds[PKC * 2 * 2048]; // [pk][hi/lo][c(4)][lane(64)][j(8)] = 32 KB

    int t = threadIdx.x;
    int w = t >> 6;
    int lane = t & 63;
    int q  = blockIdx.x >> 8;
    int rt = blockIdx.x & 255;
    if (rt * 256 >= n) return;
    int colbase = q * 64;
    int mrow = lane & 15;
    int koct = (lane >> 4) * 8;
    int rbase = rt * 256 + w * 64;

    int rows[4];
#pragma unroll
    for (int mt = 0; mt < 4; ++mt) {
        int r = rbase + mt * 16 + mrow;
        rows[mt] = (r < n) ? r : (n - 1);     // clamp: dup rows, never stored
    }

    f32x4 acc[4][4];
#pragma unroll
    for (int mt = 0; mt < 4; ++mt)
#pragma unroll
        for (int c = 0; c < 4; ++c)
            acc[mt][c] = (f32x4)(0.0f);

    // ---- A register pipeline ----
    f16x8 a16p[2][4];                 // AMODE 1: depth-2
    float4 af0[4], af1[4];            // AMODE 0: depth-1
    if (AMODE == 1) {
#pragma unroll
        for (int mt = 0; mt < 4; ++mt) {
            a16p[0][mt] = *(const f16x8*)(A16 + (size_t)rows[mt] * K + koct);
            a16p[1][mt] = *(const f16x8*)(A16 + (size_t)rows[mt] * K + 32 + koct);
        }
    } else {
#pragma unroll
        for (int mt = 0; mt < 4; ++mt) {
            const float* p = Af + (size_t)rows[mt] * K + koct;
            af0[mt] = *(const float4*)p;
            af1[mt] = *(const float4*)(p + 4);
        }
    }

#pragma unroll
    for (int ph = 0; ph < NPH; ++ph) {
        if (ph) __syncthreads();              // all waves done reading previous phase
#pragma unroll
        for (int pk = 0; pk < PKC; ++pk) {
            int kc = ph * PKC + pk;
            __builtin_amdgcn_global_load_lds(
                (const __attribute__((address_space(1))) unsigned int*)(WhG + (size_t)kc * 8192 + q * 2048 + t * 8),
                (__attribute__((address_space(3))) unsigned int*)(&Wlds[(pk * 2 + 0) * 2048 + t * 8]), 16, 0, 0);
            __builtin_amdgcn_global_load_lds(
                (const __attribute__((address_space(1))) unsigned int*)(WlG + (size_t)kc * 8192 + q * 2048 + t * 8),
                (__attribute__((address_space(3))) unsigned int*)(&Wlds[(pk * 2 + 1) * 2048 + t * 8]), 16, 0, 0);
        }
        __syncthreads();

#pragma unroll
        for (int pk = 0; pk < PKC; ++pk) {
            int kc = ph * PKC + pk;
            f16x8 ah[4], al[4];
            if (AMODE == 0) {
#pragma unroll
                for (int mt = 0; mt < 4; ++mt) {
                    float4 c0 = af0[mt], c1 = af1[mt];
                    if (kc + 1 < KC) {
                        const float* p = Af + (size_t)rows[mt] * K + (kc + 1) * 32 + koct;
                        af0[mt] = *(const float4*)p;
                        af1[mt] = *(const float4*)(p + 4);
                    }
                    float xs[8] = {c0.x, c0.y, c0.z, c0.w, c1.x, c1.y, c1.z, c1.w};
                    f16x8 H, L;
#pragma unroll
                    for (int j = 0; j < 8; ++j) {
                        _Float16 hb = (_Float16)xs[j];
                        H[j] = hb;
                        L[j] = (_Float16)(xs[j] - (float)hb);
                    }
                    ah[mt] = H;
                    al[mt] = L;
                }
            }

#pragma unroll
            for (int c = 0; c < 4; ++c) {
                f16x8 bh = *(const f16x8*)&Wlds[(pk * 2 + 0) * 2048 + c * 512 + lane * 8];
                f16x8 bl = *(const f16x8*)&Wlds[(pk * 2 + 1) * 2048 + c * 512 + lane * 8];
#pragma unroll
                for (int mt = 0; mt < 4; ++mt) {
                    if (AMODE == 1) {
                        f16x8 a = a16p[kc & 1][mt];
                        acc[mt][c] = __builtin_amdgcn_mfma_f32_16x16x32_f16(a, bh, acc[mt][c], 0, 0, 0);
                        acc[mt][c] = __builtin_amdgcn_mfma_f32_16x16x32_f16(a, bl, acc[mt][c], 0, 0, 0);
                    } else {
                        acc[mt][c] = __builtin_amdgcn_mfma_f32_16x16x32_f16(ah[mt], bh, acc[mt][c], 0, 0, 0);
                        acc[mt][c] = __builtin_amdgcn_mfma_f32_16x16x32_f16(ah[mt], bl, acc[mt][c], 0, 0, 0);
                        acc[mt][c] = __builtin_amdgcn_mfma_f32_16x16x32_f16(al[mt], bh, acc[mt][c], 0, 0, 0);
                    }
                }
            }

            if (AMODE == 1 && kc + 2 < KC) {
#pragma unroll
                for (int mt = 0; mt < 4; ++mt)
                    a16p[kc & 1][mt] = *(const f16x8*)(A16 + (size_t)rows[mt] * K + (kc + 2) * 32 + koct);
            }
        }
    }

    // ---- epilogue: C/D layout col=lane&15, row=(lane>>4)*4+reg ----
    int colq = lane & 15;
    int rowq = (lane >> 4) * 4;
#pragma unroll
    for (int c = 0; c < 4; ++c) {
        int col = colbase + c * 16 + colq;
        float b = bias[col];
#pragma unroll
        for (int mt = 0; mt < 4; ++mt) {
            int rb = rbase + mt * 16 + rowq;
#pragma unroll
            for (int r = 0; r < 4; ++r) {
                int row = rb + r;
                if (row < n) {
                    float v = acc[mt][c][r] + b;
                    if (relu) v = fmaxf(v, 0.f);
                    if (OUT16) Ch[(size_t)row * H_DIM + col] = (_Float16)v;
                    else       Cf[(size_t)row * H_DIM + col] = v;
                }
            }
        }
    }
}

// ---------------- launch ----------------

extern "C" void kernel_launch(void* const* d_in, const int* in_sizes, int n_in,
                              void* d_out, int out_size, void* d_ws, size_t ws_size,
                              hipStream_t stream) {
    const float* x     = (const float*)d_in[0];
    const int*   ei    = (const int*)d_in[1];
    const float* W_enc = (const float*)d_in[3];
    const float* b_enc = (const float*)d_in[4];
    const float* W_g   = (const float*)d_in[5];
    const float* b_g   = (const float*)d_in[6];
    const float* W_out = (const float*)d_in[7];
    const float* b_out = (const float*)d_in[8];
    float* out = (float*)d_out;

    char* ws = (char*)d_ws;
    size_t off = 0;
    auto alloc = [&](size_t bytes) -> void* {
        void* p = ws + off;
        off = (off + bytes + 255) & ~(size_t)255;
        return p;
    };
    int*       counts   = (int*)alloc((size_t)N_NODES * 4);
    int*       pos      = (int*)alloc((size_t)N_EDGES * 4);
    int2*      csr      = (int2*)alloc((size_t)N_NODES * BUCKET * 8);
    _Float16*  h16      = (_Float16*)alloc((size_t)N_NODES * H_DIM * 2);
    _Float16*  agg16    = (_Float16*)alloc((size_t)N_NODES * H_DIM * 2);
    _Float16*  whi      = (_Float16*)alloc((size_t)WCONV_TOTAL * 2);
    _Float16*  wlo      = (_Float16*)alloc((size_t)WCONV_TOTAL * 2);

    const int* src = ei;
    const int* dst = ei + N_EDGES;

    hipMemsetAsync(counts, 0, (size_t)N_NODES * 4, stream);
    hist_kernel<<<(N_EDGES + 255) / 256, 256, 0, stream>>>(dst, counts, pos, N_EDGES);
    fill_kernel<<<(N_EDGES + 255) / 256, 256, 0, stream>>>(src, pos, counts, csr, N_EDGES);
    wconv_kernel<<<(WCONV_TOTAL + 255) / 256, 256, 0, stream>>>(W_enc, W_g, W_out, whi, wlo);

    // encoder: h1 = relu(x @ W_enc + b_enc)  — KC=4 (K=128), fp32 A inline-split
    mfma_gemm<4, 0, 1><<<1024, 256, 0, stream>>>(x, (const _Float16*)nullptr,
                                                 whi, wlo, b_enc,
                                                 (float*)nullptr, h16, N_NODES, 1);
    // 3 GCN layers
    for (int l = 0; l < L_LAYERS; ++l) {
        aggregate_kernel<<<N_NODES / 4, 256, 0, stream>>>(h16, counts, csr,
                                                          agg16, N_NODES);
        mfma_gemm<8, 1, 1><<<1024, 256, 0, stream>>>((const float*)nullptr, agg16,
                                                     whi + 32768 + (size_t)l * 65536,
                                                     wlo + 32768 + (size_t)l * 65536,
                                                     b_g + (size_t)l * H_DIM,
                                                     (float*)nullptr, h16, N_NODES, 1);
    }
    // output head (no relu), f16 A, fp32 out
    mfma_gemm<8, 1, 0><<<1024, 256, 0, stream>>>((const float*)nullptr, h16,
                                                 whi + 229376, wlo + 229376, b_out,
                                                 out, (_Float16*)nullptr, N_NODES, 0);
}